// Round 12
// baseline (753.555 us; speedup 1.0000x reference)
//
#include <hip/hip_runtime.h>

#define EPS_ 1e-5f

typedef __attribute__((ext_vector_type(8))) short bf16x8;
typedef __attribute__((ext_vector_type(8))) unsigned short u16x8;
typedef __attribute__((ext_vector_type(4))) float f32x4;
typedef __attribute__((ext_vector_type(2))) float f32x2;
typedef __attribute__((address_space(3))) u16x8 lds_u16x8;
typedef __attribute__((address_space(3))) f32x4 lds_f32x4;

__device__ __forceinline__ float sigmoidf_(float v) { return 1.f / (1.f + __expf(-v)); }

__device__ __forceinline__ unsigned short f2bf(float f) {
  unsigned int u = __float_as_uint(f);
  u += 0x7fff + ((u >> 16) & 1);  // RNE
  return (unsigned short)(u >> 16);
}

__device__ __forceinline__ void cvt8_(u16x8 v, float* f) {
  union { u16x8 s; unsigned int u[4]; } uu;
  uu.s = v;
#pragma unroll
  for (int j = 0; j < 4; ++j) {
    f[2 * j] = __uint_as_float(uu.u[j] << 16);
    f[2 * j + 1] = __uint_as_float(uu.u[j] & 0xffff0000u);
  }
}

// pk-fma: float2 fused multiply-add -> v_pk_fma_f32 on gfx950
__device__ __forceinline__ f32x2 pkfma_(f32x2 a, f32x2 b, f32x2 c) {
#if __has_builtin(__builtin_elementwise_fma)
  return __builtin_elementwise_fma(a, b, c);
#else
  return (f32x2){fmaf(a.x, b.x, c.x), fmaf(a.y, b.y, c.y)};
#endif
}

// async global->LDS, 16B per lane; LDS dest is wave-uniform base + lane*16
__device__ __forceinline__ void gload16(const void* g, void* l) {
  __builtin_amdgcn_global_load_lds((const __attribute__((address_space(1))) unsigned int*)(g),
                                   (__attribute__((address_space(3))) unsigned int*)(l), 16, 0, 0);
}

// ---------------------------------------------------------------- gate stage 2
__global__ void gate_kernel(const float* __restrict__ partial, const float* __restrict__ gw,
                            const float* __restrict__ gb, float* __restrict__ gout) {
  int b = blockIdx.x, t = threadIdx.x;
  float s = partial[b * 256 + t] * gw[t];
#pragma unroll
  for (int off = 32; off; off >>= 1) s += __shfl_down(s, off, 64);
  __shared__ float red[4];
  if ((t & 63) == 0) red[t >> 6] = s;
  __syncthreads();
  if (t == 0) {
    float tot = (red[0] + red[1]) + (red[2] + red[3]);
    gout[b] = sigmoidf_(tot * (1.f / 16384.f) + gb[0]);
  }
}

// ---------------------------------------------------------------- weight transform (dense conv)
__global__ void wtrans_kernel(const float* __restrict__ w, unsigned short* __restrict__ wT) {
  int n = blockIdx.x * 256 + threadIdx.x;  // 589824
  int c = n & 31, oc = (n >> 5) & 255, t9 = n >> 13;
  int cb = t9 / 9, tap = t9 - cb * 9;
  wT[n] = f2bf(w[(oc * 256 + cb * 32 + c) * 9 + tap]);
}

// ---------------------------------------------------------------- kernelgen weight prep
// w1f: [g=32][tp=9][o=8][ic=8] fp32, BN-scale folded in (ic pairs -> f32x2 lanes).
// b1f: [c=256] BN-folded bias.  w2t: [c=256][28] (n<25 valid, zero-padded) transposed 1x1.
// zb: 16 floats (64B) of zeros — halo source for conv's global_load_lds.
__global__ void kprep_kernel(const float* __restrict__ w1, const float* __restrict__ b1,
                             const float* __restrict__ bng, const float* __restrict__ bnb,
                             const float* __restrict__ bnm, const float* __restrict__ bnv,
                             const float* __restrict__ w2, float* __restrict__ w1f,
                             float* __restrict__ b1f, float* __restrict__ w2t,
                             float* __restrict__ zb) {
  int n = blockIdx.x * 256 + threadIdx.x;  // 72 blocks -> 18432 threads
  if (n < 16) zb[n] = 0.f;
  if (n < 256) {
    float s = bng[n] * rsqrtf(bnv[n] + EPS_);
    b1f[n] = (b1[n] - bnm[n]) * s + bnb[n];
  }
  if (n < 18432) {
    int ic = n & 7, o = (n >> 3) & 7, tp = (n >> 6) % 9, g = n / 576;
    int c = g * 8 + o;
    float s = bng[c] * rsqrtf(bnv[c] + EPS_);
    w1f[n] = w1[c * 72 + ic * 9 + tp] * s;
  }
  if (n < 7168) {
    int nn = n % 28, c = n / 28;
    w2t[n] = (nn < 25) ? w2[nn * 256 + c] : 0.f;
  }
}

// ---------------------------------------------------------------- x fp32 NCHW -> xT bf16 NHWC
// + fused GAP partial sums (atomicAdd into partial[b*256+ch]; saves a full x re-read).
// grid: 256 px-tiles(64) x 8 b = 2048 blocks
__global__ __launch_bounds__(256) void transpose_kernel(const float* __restrict__ x,
                                                        unsigned short* __restrict__ xT,
                                                        float* __restrict__ partial) {
  int blk = blockIdx.x;
  int tile = blk & 255, b = blk >> 8;
  int px0 = tile * 64;
  __shared__ unsigned int tr[64 * 130];  // [px][128 ch-pair words + 2 pad]
  for (int i = threadIdx.x; i < 1024; i += 256) {
    int ch2 = i >> 3, pc = i & 7;
    const float* p0 = x + (((size_t)b * 256 + ch2 * 2) << 14) + px0 + pc * 8;
    const float4* a4 = (const float4*)p0;
    const float4* b4 = (const float4*)(p0 + 16384);
    float4 a0 = a4[0], a1 = a4[1], b0 = b4[0], b1 = b4[1];
    float fa[8] = {a0.x, a0.y, a0.z, a0.w, a1.x, a1.y, a1.z, a1.w};
    float fb[8] = {b0.x, b0.y, b0.z, b0.w, b1.x, b1.y, b1.z, b1.w};
    float sa = 0.f, sb = 0.f;
#pragma unroll
    for (int j = 0; j < 8; ++j) {
      sa += fa[j];
      sb += fb[j];
      unsigned int w = (unsigned int)f2bf(fa[j]) | ((unsigned int)f2bf(fb[j]) << 16);
      tr[(pc * 8 + j) * 130 + ch2] = w;
    }
    // 8-lane group reduce (lanes pc=0..7 share ch2), then one atomic per channel
    sa += __shfl_down(sa, 4, 8); sa += __shfl_down(sa, 2, 8); sa += __shfl_down(sa, 1, 8);
    sb += __shfl_down(sb, 4, 8); sb += __shfl_down(sb, 2, 8); sb += __shfl_down(sb, 1, 8);
    if ((threadIdx.x & 7) == 0) {
      atomicAdd(&partial[(b << 8) + ch2 * 2], sa);
      atomicAdd(&partial[(b << 8) + ch2 * 2 + 1], sb);
    }
  }
  __syncthreads();
  for (int i = threadIdx.x; i < 2048; i += 256) {
    int px = i >> 5, kc = i & 31;
    uint4 v = *(uint4*)&tr[px * 130 + kc * 4];
    *(uint4*)(xT + ((((size_t)b << 14)) + px0 + px) * 256 + kc * 8) = v;
  }
}

// ---------------------------------------------------------------- fused bodies
// kernelgen body (pk-math): full image (8 ch-rounds) per block, softmax fused.
// LDS [18x18 px][32 ch + 8 pad] = 25,920B. PAD MUST KEEP 16B ALIGNMENT:
// byte addr = 80p + 16s (pad 40). R11's pad-36 gave 72p+16s -> 8B-aligned for odd p
// -> misaligned ds_write_b128 -> corrupted kern (correctness failure).
// setprio(1): kg is a long-lived critical-path block.
__device__ __forceinline__ void kernelgen_body(int kblk, const unsigned short* __restrict__ xT,
                                               const float* __restrict__ w1f,
                                               const float* __restrict__ b1f,
                                               const float* __restrict__ w2t,
                                               const float* __restrict__ b2,
                                               float* __restrict__ kern, char* smemc) {
  unsigned short* xs = (unsigned short*)smemc;  // 25,920B
  int t = kblk & 63, b = kblk >> 6;
  int px0 = (t & 7) * 16, py0 = (t >> 3) * 16;
  int lx = threadIdx.x & 15, ly = threadIdx.x >> 4;
  __builtin_amdgcn_s_setprio(1);
  f32x2 acc2[13];
#pragma unroll
  for (int j = 0; j < 12; ++j) acc2[j] = (f32x2){b2[2 * j], b2[2 * j + 1]};
  acc2[12] = (f32x2){b2[24], 0.f};

#pragma unroll 1
  for (int gq = 0; gq < 8; ++gq) {
    __syncthreads();
    for (int i = threadIdx.x; i < 1296; i += 256) {
      int s = i & 3, p = i >> 2;
      int yy = py0 + p / 18 - 1, xx = px0 + (p % 18) - 1;
      u16x8 v = (u16x8)(unsigned short)0;
      if (((unsigned)yy < 128u) && ((unsigned)xx < 128u))
        v = *(const u16x8*)(xT + (((size_t)(b << 14)) + yy * 128 + xx) * 256 + gq * 32 + s * 8);
      *(lds_u16x8*)(&xs[p * 40 + s * 8]) = v;
    }
    __syncthreads();
#pragma unroll
    for (int s = 0; s < 4; ++s) {
      int g = gq * 4 + s;
      const float* wg = w1f + g * 576;  // [tp][o][ic], wave-uniform -> s_load
      const float* bp = b1f + g * 8;
      f32x2 h2[8];
#pragma unroll
      for (int o = 0; o < 8; ++o) h2[o] = (f32x2){bp[o], 0.f};
#pragma unroll
      for (int tp = 0; tp < 9; ++tp) {
        union { u16x8 s8; unsigned int u[4]; } uu;
        uu.s8 = *(lds_u16x8*)(&xs[((ly + tp / 3) * 18 + lx + tp % 3) * 40 + s * 8]);
        f32x2 xv2[4];
#pragma unroll
        for (int j = 0; j < 4; ++j)
          xv2[j] = (f32x2){__uint_as_float(uu.u[j] << 16),
                           __uint_as_float(uu.u[j] & 0xffff0000u)};
        const f32x2* wt2 = (const f32x2*)(wg + tp * 64);
#pragma unroll
        for (int o = 0; o < 8; ++o)
#pragma unroll
          for (int j = 0; j < 4; ++j) h2[o] = pkfma_(xv2[j], wt2[o * 4 + j], h2[o]);
      }
#pragma unroll
      for (int o = 0; o < 8; ++o) {
        float h = h2[o].x + h2[o].y;
        float sv = h * sigmoidf_(h);
        f32x2 sv2 = (f32x2){sv, sv};
        const f32x2* w2p2 = (const f32x2*)(w2t + (g * 8 + o) * 28);  // padded pairs
#pragma unroll
        for (int j = 0; j < 13; ++j) acc2[j] = pkfma_(sv2, w2p2[j], acc2[j]);
      }
    }
  }
  float a[25];
#pragma unroll
  for (int j = 0; j < 12; ++j) { a[2 * j] = acc2[j].x; a[2 * j + 1] = acc2[j].y; }
  a[24] = acc2[12].x;
  float m = a[0];
#pragma unroll
  for (int n = 1; n < 25; ++n) m = fmaxf(m, a[n]);
  float sum = 0.f;
#pragma unroll
  for (int n = 0; n < 25; ++n) { a[n] = __expf(a[n] - m); sum += a[n]; }
  float inv = 1.f / sum;
  size_t base = (((size_t)b * 25) << 14) + (py0 + ly) * 128 + px0 + lx;
#pragma unroll
  for (int n = 0; n < 25; ++n) kern[base + ((size_t)n << 14)] = a[n] * inv;
  __builtin_amdgcn_s_setprio(0);
}

// conv body: M=128 px (one row) x N=64 oc (quarter); K = 24 rows x 32 ch.
// RING-3 (24,960B LDS) + 64-oc split (4096 blocks) -> acc[8] = 32 AGPR so the
// (256,6) budget (85 unified regs/wave) holds WITHOUT the R6 spill. WAVE =
// 128px x 16oc: distinct oc band per wave, direct f32x4 stores. Per row R:
// [vmcnt(6): rows R+1,R+2 in flight] [barrier] [3kw x {1 bfrag, 8x(ds_read, MFMA)}]
// [barrier] [stage row R+3 into slot R%3]. Tail vmcnt(3)/vmcnt(0).
// Swizzle s = k ^ ((px>>1)&3) on source; XCD swizzle: 512 consecutive nb per XCD.
__device__ __forceinline__ void conv_body(int cblk, const unsigned short* __restrict__ xT,
                                          const unsigned short* __restrict__ wT,
                                          const float* __restrict__ bb,
                                          const float* __restrict__ bng,
                                          const float* __restrict__ bnb,
                                          const float* __restrict__ bnm,
                                          const float* __restrict__ bnv,
                                          const unsigned short* __restrict__ zbuf,
                                          float* __restrict__ out, char* smemc) {
  int nb = ((cblk & 7) << 9) | (cblk >> 3);  // XCD swizzle (4096 % 8 == 0)
  int ocq = nb & 3, y = (nb >> 2) & 127, b = nb >> 9;
  int lane = threadIdx.x & 63, wid = threadIdx.x >> 6;
  int m_l = lane & 15, kgrp = lane >> 4;

  unsigned short* xs = (unsigned short*)smemc;  // ring: 3 x 8320B row slots
  const char* zc = (const char*)zbuf;

  // per-thread staging constants: wave w covers granules [w*130, w*130+130)
  int g0 = wid * 130 + lane, g1 = g0 + 64, g2 = wid * 130 + 128 + lane;  // g2: lane<2
  int px0_ = g0 >> 2, k0_ = g0 & 3, s0_ = k0_ ^ ((px0_ >> 1) & 3), gx0 = px0_ - 1;
  int px1_ = g1 >> 2, k1_ = g1 & 3, s1_ = k1_ ^ ((px1_ >> 1) & 3), gx1 = px1_ - 1;
  int px2_ = g2 >> 2, k2_ = g2 & 3, s2_ = k2_ ^ ((px2_ >> 1) & 3), gx2 = px2_ - 1;
  bool ok0 = (unsigned)gx0 < 128u, ok1 = (unsigned)gx1 < 128u, ok2 = (unsigned)gx2 < 128u;
  int off0 = gx0 * 512 + s0_ * 16, off1 = gx1 * 512 + s1_ * 16, off2 = gx2 * 512 + s2_ * 16;
  int d0 = (wid * 130) * 16, d1 = d0 + 1024, d2 = d0 + 2048;  // wave-uniform LDS bases

#define STAGE_ROW(slotB_, cbn_, khn_)                                                       \
  do {                                                                                      \
    int gy_ = y + (khn_)-1;                                                                 \
    bool gyok_ = ((unsigned)gy_ < 128u);                                                    \
    const char* rb_ =                                                                       \
        (const char*)xT + (((size_t)b << 14) + (size_t)(gy_ & 127) * 128) * 512 + (cbn_)*64;\
    gload16((gyok_ && ok0) ? rb_ + off0 : zc, smemc + (slotB_) + d0);                       \
    gload16((gyok_ && ok1) ? rb_ + off1 : zc, smemc + (slotB_) + d1);                       \
    if (lane < 2) gload16((gyok_ && ok2) ? rb_ + off2 : zc, smemc + (slotB_) + d2);         \
  } while (0)

  f32x4 acc[8];
#pragma unroll
  for (int mt = 0; mt < 8; ++mt) acc[mt] = (f32x4)0.f;

  // prologue: stage rows 0..2 (row r -> cb=r/3, kh=r%3, slot r%3)
  STAGE_ROW(0, 0, 0);
  STAGE_ROW(8320, 0, 1);
  STAGE_ROW(16640, 0, 2);

  // per-thread bfrag base (ushorts); wave owns oc band [ocq*64 + wid*16, +16)
  int oc0 = ocq * 64 + wid * 16;
  const unsigned short* wTb = wT + ((size_t)(oc0 + m_l) * 32 + kgrp * 8);
  int khn = 0, cbn = 1;  // next row to stage = 3 -> cb1,kh0
  int slot = 0;          // R % 3

#pragma unroll 1
  for (int R = 0; R < 24; ++R) {
    if (R < 22) {
      asm volatile("s_waitcnt vmcnt(6)" ::: "memory");  // row R landed; R+1,R+2 in flight
    } else if (R == 22) {
      asm volatile("s_waitcnt vmcnt(3)" ::: "memory");
    } else {
      asm volatile("s_waitcnt vmcnt(0)" ::: "memory");
    }
    __builtin_amdgcn_s_barrier();
    asm volatile("" ::: "memory");
    const unsigned short* xb = xs + slot * 4160;
#pragma unroll
    for (int kw = 0; kw < 3; ++kw) {
      bf16x8 bfrag = *(const bf16x8*)(wTb + (size_t)(R * 3 + kw) * 8192);
#pragma unroll
      for (int mt = 0; mt < 8; ++mt) {
        int apx = mt * 16 + m_l + kw;
        int kk = kgrp ^ ((apx >> 1) & 3);
        bf16x8 af = *(__attribute__((address_space(3))) bf16x8*)(&xb[apx * 32 + kk * 8]);
        acc[mt] = __builtin_amdgcn_mfma_f32_16x16x32_bf16(af, bfrag, acc[mt], 0, 0, 0);
      }
    }
    __builtin_amdgcn_s_barrier();  // slot R%3 free
    asm volatile("" ::: "memory");
    if (R < 21) {
      STAGE_ROW((size_t)slot * 8320, cbn, khn);
      ++khn;
      if (khn == 3) { khn = 0; ++cbn; }
    }
    slot = (slot == 2) ? 0 : slot + 1;
  }
#undef STAGE_ROW

  // epilogue: direct stores — wave owns oc rows [oc0, oc0+16), all 128 px.
  int oc = oc0 + m_l;
  float s_ = bng[oc] * rsqrtf(bnv[oc] + EPS_);
  float bias_ = bnb[oc] + (bb[oc] - bnm[oc]) * s_;
  size_t obase = (((size_t)(b * 256 + oc)) << 14) + y * 128 + kgrp * 4;
#pragma unroll
  for (int mt = 0; mt < 8; ++mt) {
    f32x4 v = acc[mt];
    float o4[4];
#pragma unroll
    for (int r = 0; r < 4; ++r) {
      float hv = v[r] * s_ + bias_;
      o4[r] = hv * sigmoidf_(hv);
    }
    *(f32x4*)(out + obase + mt * 16) = (f32x4){o4[0], o4[1], o4[2], o4[3]};
  }
}

// ---------------------------------------------------------------- fused dispatch
// blocks [0,kgN) run kernelgen (VALU-bound, prio 1), the rest run conv (MFMA-bound).
// smem = max(conv 24,960, kg 25,920) = 25,920B -> 6 blocks/CU (155,520 <= 163,840):
// 2 kg + 4 conv per CU -> conv keeps its standalone residency while kg co-schedules
// on the VALU pipe (fixes R9/R10's residency theft).
__global__ __launch_bounds__(256, 6) void fused_kernel(
    int kgN, const unsigned short* __restrict__ xT, const unsigned short* __restrict__ wT,
    const float* __restrict__ w1f, const float* __restrict__ b1f, const float* __restrict__ w2t,
    const float* __restrict__ b2, float* __restrict__ kern, const float* __restrict__ bb,
    const float* __restrict__ bng, const float* __restrict__ bnb, const float* __restrict__ bnm,
    const float* __restrict__ bnv, const unsigned short* __restrict__ zbuf,
    float* __restrict__ out) {
  __shared__ char smem[25920];
  int blk = (int)blockIdx.x;
  if (blk < kgN) {
    kernelgen_body(blk, xT, w1f, b1f, w2t, b2, kern, smem);
  } else {
    conv_body(blk - kgN, xT, wT, bb, bng, bnb, bnm, bnv, zbuf, out, smem);
  }
}

// ---------------------------------------------------------------- CARAFE + blend (RMW on out)
// grid: 16 ch-groups x 8 bx x 4 by x 8 b = 4096 blocks; tile 16ch x 32y x 16x
__global__ __launch_bounds__(256) void carafe_blend_kernel(
    const unsigned short* __restrict__ xT, const float* __restrict__ kern,
    const float* __restrict__ gq, float* __restrict__ out) {
  int blk = blockIdx.x;
  int ocg = blk & 15, bx = (blk >> 4) & 7, by = (blk >> 7) & 3, b = blk >> 9;
  __shared__ unsigned short xc[720 * 16];  // [36x20 px][16 ch]
  for (int i = threadIdx.x; i < 1440; i += 256) {
    int half = i & 1, p = i >> 1;
    int py = p / 20, pxx = p - py * 20;
    int yy = by * 32 + py - 2, xx = bx * 16 + pxx - 2;
    yy = yy < 0 ? -yy : (yy > 127 ? 254 - yy : yy);
    xx = xx < 0 ? -xx : (xx > 127 ? 254 - xx : xx);
    *(lds_u16x8*)(&xc[p * 16 + half * 8]) =
        *(const u16x8*)(xT + (((size_t)(b << 14)) + yy * 128 + xx) * 256 + ocg * 16 + half * 8);
  }
  __syncthreads();
  int lx = threadIdx.x & 15, y0 = (threadIdx.x >> 4) * 2;
  float gv = gq[b];
  int gy0 = by * 32 + y0, gx = bx * 16 + lx;
  float kv0[25], kv1[25];
  size_t kb = (((size_t)b * 25) << 14) + gy0 * 128 + gx;
#pragma unroll
  for (int n = 0; n < 25; ++n) {
    kv0[n] = kern[kb + ((size_t)n << 14)];
    kv1[n] = kern[kb + ((size_t)n << 14) + 128];
  }
  float car0[16], car1[16];
#pragma unroll
  for (int c = 0; c < 16; ++c) { car0[c] = 0.f; car1[c] = 0.f; }
#pragma unroll
  for (int n = 0; n < 25; ++n) {
    int ki = n / 5, kj = n - ki * 5;
    int p0 = (y0 + ki) * 20 + lx + kj;
    float f0[16], f1[16];
    cvt8_(*(lds_u16x8*)(&xc[p0 * 16]), &f0[0]);
    cvt8_(*(lds_u16x8*)(&xc[p0 * 16 + 8]), &f0[8]);
    cvt8_(*(lds_u16x8*)(&xc[(p0 + 20) * 16]), &f1[0]);
    cvt8_(*(lds_u16x8*)(&xc[(p0 + 20) * 16 + 8]), &f1[8]);
#pragma unroll
    for (int c = 0; c < 16; ++c) {
      car0[c] = fmaf(f0[c], kv0[n], car0[c]);
      car1[c] = fmaf(f1[c], kv1[n], car1[c]);
    }
  }
#pragma unroll
  for (int c = 0; c < 16; ++c) {
    size_t ob = (((size_t)(b * 256 + ocg * 16 + c)) << 14) + gy0 * 128 + gx;
    float st0 = out[ob], st1 = out[ob + 128];
    out[ob] = fmaf(gv, car0[c] - st0, st0);
    out[ob + 128] = fmaf(gv, car1[c] - st1, st1);
  }
}

// ---------------------------------------------------------------- launcher
extern "C" void kernel_launch(void* const* d_in, const int* in_sizes, int n_in,
                              void* d_out, int out_size, void* d_ws, size_t ws_size,
                              hipStream_t stream) {
  const float* x      = (const float*)d_in[0];
  const float* ke_w1  = (const float*)d_in[1];
  const float* ke_b1  = (const float*)d_in[2];
  const float* ke_bng = (const float*)d_in[3];
  const float* ke_bnb = (const float*)d_in[4];
  const float* ke_bnm = (const float*)d_in[5];
  const float* ke_bnv = (const float*)d_in[6];
  const float* ke_w2  = (const float*)d_in[7];
  const float* ke_b2  = (const float*)d_in[8];
  const float* bs_w   = (const float*)d_in[9];
  const float* bs_b   = (const float*)d_in[10];
  const float* bs_bng = (const float*)d_in[11];
  const float* bs_bnb = (const float*)d_in[12];
  const float* bs_bnm = (const float*)d_in[13];
  const float* bs_bnv = (const float*)d_in[14];
  const float* g_w    = (const float*)d_in[15];
  const float* g_b    = (const float*)d_in[16];
  float* outp = (float*)d_out;

  char* ws = (char*)d_ws;
  float* kern        = (float*)(ws);                      // 13,107,200 B
  float* partial     = (float*)(ws + 13107200);           // 8,192 B
  float* gout        = (float*)(ws + 13115392);           // bytes 0-31 of 256B slot
  float* zbuff       = (float*)(ws + 13115392 + 128);     // 64B zero pad
  unsigned short* wT = (unsigned short*)(ws + 13115648);  // 1,179,648 B
  unsigned short* xT = (unsigned short*)(ws + 14295296);  // 67,108,864 B -> 81,404,160 total

  // kprep tables (103,424 B): prefer ws tail (enables fused launch: conv writes out
  // concurrently, so tables must NOT alias d_out). If ws is too small, fall back to
  // dead d_out space + serial launches.
  const size_t USED = 81404160;
  bool bigws = ws_size >= USED + 131072;
  float *w1f, *b1f, *w2t;
  if (bigws) {
    w1f = (float*)(ws + USED);            // 73,728 B
    b1f = (float*)(ws + USED + 73728);    //  1,024 B
    w2t = (float*)(ws + USED + 74752);    // 28,672 B
  } else {
    w1f = (float*)((char*)d_out + 52428800);
    b1f = (float*)((char*)d_out + 52502528);
    w2t = (float*)((char*)d_out + 52503552);
  }

  hipMemsetAsync(partial, 0, 2048 * sizeof(float), stream);  // GAP accumulators
  kprep_kernel<<<72, 256, 0, stream>>>(ke_w1, ke_b1, ke_bng, ke_bnb, ke_bnm, ke_bnv, ke_w2,
                                       w1f, b1f, w2t, zbuff);
  wtrans_kernel<<<2304, 256, 0, stream>>>(bs_w, wT);
  transpose_kernel<<<2048, 256, 0, stream>>>(x, xT, partial);
  gate_kernel<<<8, 256, 0, stream>>>(partial, g_w, g_b, gout);

  if (bigws) {
    // fused: 512 kernelgen blocks (first, all co-resident) + 4096 conv blocks
    fused_kernel<<<4608, 256, 0, stream>>>(512, xT, wT, w1f, b1f, w2t, ke_b2, kern, bs_b,
                                           bs_bng, bs_bnb, bs_bnm, bs_bnv,
                                           (const unsigned short*)zbuff, outp);
  } else {
    // serial fallback: tables live in d_out (dead until conv runs after kernelgen)
    fused_kernel<<<512, 256, 0, stream>>>(512, xT, wT, w1f, b1f, w2t, ke_b2, kern, bs_b,
                                          bs_bng, bs_bnb, bs_bnm, bs_bnv,
                                          (const unsigned short*)zbuff, outp);
    fused_kernel<<<4096, 256, 0, stream>>>(0, xT, wT, w1f, b1f, w2t, ke_b2, kern, bs_b,
                                           bs_bng, bs_bnb, bs_bnm, bs_bnv,
                                           (const unsigned short*)zbuff, outp);
  }
  carafe_blend_kernel<<<4096, 256, 0, stream>>>(xT, kern, gout, outp);
}

// Round 13
// 658.741 us; speedup vs baseline: 1.1439x; 1.1439x over previous
//
#include <hip/hip_runtime.h>

#define EPS_ 1e-5f

typedef __attribute__((ext_vector_type(8))) short bf16x8;
typedef __attribute__((ext_vector_type(8))) unsigned short u16x8;
typedef __attribute__((ext_vector_type(4))) float f32x4;
typedef __attribute__((ext_vector_type(2))) float f32x2;
typedef __attribute__((address_space(3))) u16x8 lds_u16x8;
typedef __attribute__((address_space(3))) f32x4 lds_f32x4;

__device__ __forceinline__ float sigmoidf_(float v) { return 1.f / (1.f + __expf(-v)); }

__device__ __forceinline__ unsigned short f2bf(float f) {
  unsigned int u = __float_as_uint(f);
  u += 0x7fff + ((u >> 16) & 1);  // RNE
  return (unsigned short)(u >> 16);
}

__device__ __forceinline__ void cvt8_(u16x8 v, float* f) {
  union { u16x8 s; unsigned int u[4]; } uu;
  uu.s = v;
#pragma unroll
  for (int j = 0; j < 4; ++j) {
    f[2 * j] = __uint_as_float(uu.u[j] << 16);
    f[2 * j + 1] = __uint_as_float(uu.u[j] & 0xffff0000u);
  }
}

// pk-fma: float2 fused multiply-add -> v_pk_fma_f32 on gfx950
__device__ __forceinline__ f32x2 pkfma_(f32x2 a, f32x2 b, f32x2 c) {
#if __has_builtin(__builtin_elementwise_fma)
  return __builtin_elementwise_fma(a, b, c);
#else
  return (f32x2){fmaf(a.x, b.x, c.x), fmaf(a.y, b.y, c.y)};
#endif
}

// async global->LDS, 16B per lane; LDS dest is wave-uniform base + lane*16
__device__ __forceinline__ void gload16(const void* g, void* l) {
  __builtin_amdgcn_global_load_lds((const __attribute__((address_space(1))) unsigned int*)(g),
                                   (__attribute__((address_space(3))) unsigned int*)(l), 16, 0, 0);
}

// ---------------------------------------------------------------- gate stage 2
__global__ void gate_kernel(const float* __restrict__ partial, const float* __restrict__ gw,
                            const float* __restrict__ gb, float* __restrict__ gout) {
  int b = blockIdx.x, t = threadIdx.x;
  float s = partial[b * 256 + t] * gw[t];
#pragma unroll
  for (int off = 32; off; off >>= 1) s += __shfl_down(s, off, 64);
  __shared__ float red[4];
  if ((t & 63) == 0) red[t >> 6] = s;
  __syncthreads();
  if (t == 0) {
    float tot = (red[0] + red[1]) + (red[2] + red[3]);
    gout[b] = sigmoidf_(tot * (1.f / 16384.f) + gb[0]);
  }
}

// ---------------------------------------------------------------- merged prep
// blocks [0,2304): wtrans (dense conv weights -> bf16 [cb][tap][oc][c] layout)
// blocks [2304,2376): kernelgen weight prep (BN-folded w1f/b1f, transposed w2t, zbuff)
__global__ void prep_kernel(const float* __restrict__ w, unsigned short* __restrict__ wT,
                            const float* __restrict__ w1, const float* __restrict__ b1,
                            const float* __restrict__ bng, const float* __restrict__ bnb,
                            const float* __restrict__ bnm, const float* __restrict__ bnv,
                            const float* __restrict__ w2, float* __restrict__ w1f,
                            float* __restrict__ b1f, float* __restrict__ w2t,
                            float* __restrict__ zb) {
  int blk = blockIdx.x;
  if (blk < 2304) {
    int n = blk * 256 + threadIdx.x;  // 589824
    int c = n & 31, oc = (n >> 5) & 255, t9 = n >> 13;
    int cb = t9 / 9, tap = t9 - cb * 9;
    wT[n] = f2bf(w[(oc * 256 + cb * 32 + c) * 9 + tap]);
  } else {
    int n = (blk - 2304) * 256 + threadIdx.x;  // 18432
    if (n < 16) zb[n] = 0.f;
    if (n < 256) {
      float s = bng[n] * rsqrtf(bnv[n] + EPS_);
      b1f[n] = (b1[n] - bnm[n]) * s + bnb[n];
    }
    if (n < 18432) {
      int ic = n & 7, o = (n >> 3) & 7, tp = (n >> 6) % 9, g = n / 576;
      int c = g * 8 + o;
      float s = bng[c] * rsqrtf(bnv[c] + EPS_);
      w1f[n] = w1[c * 72 + ic * 9 + tp] * s;
    }
    if (n < 7168) {
      int nn = n % 28, c = n / 28;
      w2t[n] = (nn < 25) ? w2[nn * 256 + c] : 0.f;
    }
  }
}

// ---------------------------------------------------------------- x fp32 NCHW -> xT bf16 NHWC
// + fused GAP partial sums (atomicAdd into partial[b*256+ch]; saves a full x re-read).
// grid: 256 px-tiles(64) x 8 b = 2048 blocks
__global__ __launch_bounds__(256) void transpose_kernel(const float* __restrict__ x,
                                                        unsigned short* __restrict__ xT,
                                                        float* __restrict__ partial) {
  int blk = blockIdx.x;
  int tile = blk & 255, b = blk >> 8;
  int px0 = tile * 64;
  __shared__ unsigned int tr[64 * 130];  // [px][128 ch-pair words + 2 pad]
  for (int i = threadIdx.x; i < 1024; i += 256) {
    int ch2 = i >> 3, pc = i & 7;
    const float* p0 = x + (((size_t)b * 256 + ch2 * 2) << 14) + px0 + pc * 8;
    const float4* a4 = (const float4*)p0;
    const float4* b4 = (const float4*)(p0 + 16384);
    float4 a0 = a4[0], a1 = a4[1], b0 = b4[0], b1 = b4[1];
    float fa[8] = {a0.x, a0.y, a0.z, a0.w, a1.x, a1.y, a1.z, a1.w};
    float fb[8] = {b0.x, b0.y, b0.z, b0.w, b1.x, b1.y, b1.z, b1.w};
    float sa = 0.f, sb = 0.f;
#pragma unroll
    for (int j = 0; j < 8; ++j) {
      sa += fa[j];
      sb += fb[j];
      unsigned int w = (unsigned int)f2bf(fa[j]) | ((unsigned int)f2bf(fb[j]) << 16);
      tr[(pc * 8 + j) * 130 + ch2] = w;
    }
    // 8-lane group reduce (lanes pc=0..7 share ch2), then one atomic per channel
    sa += __shfl_down(sa, 4, 8); sa += __shfl_down(sa, 2, 8); sa += __shfl_down(sa, 1, 8);
    sb += __shfl_down(sb, 4, 8); sb += __shfl_down(sb, 2, 8); sb += __shfl_down(sb, 1, 8);
    if ((threadIdx.x & 7) == 0) {
      atomicAdd(&partial[(b << 8) + ch2 * 2], sa);
      atomicAdd(&partial[(b << 8) + ch2 * 2 + 1], sb);
    }
  }
  __syncthreads();
  for (int i = threadIdx.x; i < 2048; i += 256) {
    int px = i >> 5, kc = i & 31;
    uint4 v = *(uint4*)&tr[px * 130 + kc * 4];
    *(uint4*)(xT + ((((size_t)b << 14)) + px0 + px) * 256 + kc * 8) = v;
  }
}

// ---------------------------------------------------------------- fused bodies (R10 config)
// kernelgen body (pk-math, pad 40 = 16B-aligned LDS): full image (8 ch-rounds) per
// block, softmax fused. setprio(1): kg is a long-lived critical-path block.
__device__ __forceinline__ void kernelgen_body(int kblk, const unsigned short* __restrict__ xT,
                                               const float* __restrict__ w1f,
                                               const float* __restrict__ b1f,
                                               const float* __restrict__ w2t,
                                               const float* __restrict__ b2,
                                               float* __restrict__ kern, char* smemc) {
  unsigned short* xs = (unsigned short*)smemc;  // [18x18 px][32 ch + 8 pad] = 25,920B
  int t = kblk & 63, b = kblk >> 6;
  int px0 = (t & 7) * 16, py0 = (t >> 3) * 16;
  int lx = threadIdx.x & 15, ly = threadIdx.x >> 4;
  __builtin_amdgcn_s_setprio(1);
  f32x2 acc2[13];
#pragma unroll
  for (int j = 0; j < 12; ++j) acc2[j] = (f32x2){b2[2 * j], b2[2 * j + 1]};
  acc2[12] = (f32x2){b2[24], 0.f};

#pragma unroll 1
  for (int gq = 0; gq < 8; ++gq) {
    __syncthreads();
    for (int i = threadIdx.x; i < 1296; i += 256) {
      int s = i & 3, p = i >> 2;
      int yy = py0 + p / 18 - 1, xx = px0 + (p % 18) - 1;
      u16x8 v = (u16x8)(unsigned short)0;
      if (((unsigned)yy < 128u) && ((unsigned)xx < 128u))
        v = *(const u16x8*)(xT + (((size_t)(b << 14)) + yy * 128 + xx) * 256 + gq * 32 + s * 8);
      *(lds_u16x8*)(&xs[p * 40 + s * 8]) = v;
    }
    __syncthreads();
#pragma unroll
    for (int s = 0; s < 4; ++s) {
      int g = gq * 4 + s;
      const float* wg = w1f + g * 576;  // [tp][o][ic], wave-uniform -> s_load
      const float* bp = b1f + g * 8;
      f32x2 h2[8];
#pragma unroll
      for (int o = 0; o < 8; ++o) h2[o] = (f32x2){bp[o], 0.f};
#pragma unroll
      for (int tp = 0; tp < 9; ++tp) {
        union { u16x8 s8; unsigned int u[4]; } uu;
        uu.s8 = *(lds_u16x8*)(&xs[((ly + tp / 3) * 18 + lx + tp % 3) * 40 + s * 8]);
        f32x2 xv2[4];
#pragma unroll
        for (int j = 0; j < 4; ++j)
          xv2[j] = (f32x2){__uint_as_float(uu.u[j] << 16),
                           __uint_as_float(uu.u[j] & 0xffff0000u)};
        const f32x2* wt2 = (const f32x2*)(wg + tp * 64);
#pragma unroll
        for (int o = 0; o < 8; ++o)
#pragma unroll
          for (int j = 0; j < 4; ++j) h2[o] = pkfma_(xv2[j], wt2[o * 4 + j], h2[o]);
      }
#pragma unroll
      for (int o = 0; o < 8; ++o) {
        float h = h2[o].x + h2[o].y;
        float sv = h * sigmoidf_(h);
        f32x2 sv2 = (f32x2){sv, sv};
        const f32x2* w2p2 = (const f32x2*)(w2t + (g * 8 + o) * 28);  // padded pairs
#pragma unroll
        for (int j = 0; j < 13; ++j) acc2[j] = pkfma_(sv2, w2p2[j], acc2[j]);
      }
    }
  }
  float a[25];
#pragma unroll
  for (int j = 0; j < 12; ++j) { a[2 * j] = acc2[j].x; a[2 * j + 1] = acc2[j].y; }
  a[24] = acc2[12].x;
  float m = a[0];
#pragma unroll
  for (int n = 1; n < 25; ++n) m = fmaxf(m, a[n]);
  float sum = 0.f;
#pragma unroll
  for (int n = 0; n < 25; ++n) { a[n] = __expf(a[n] - m); sum += a[n]; }
  float inv = 1.f / sum;
  size_t base = (((size_t)b * 25) << 14) + (py0 + ly) * 128 + px0 + lx;
#pragma unroll
  for (int n = 0; n < 25; ++n) kern[base + ((size_t)n << 14)] = a[n] * inv;
  __builtin_amdgcn_s_setprio(0);
}

// conv body (R10 config): M=128 px x N=128 oc; K = 24 rows x 32 ch. WAVE = 128px x
// 32oc (mt=8, nt=2). ROW-PAIR RING-4 PIPELINE: per pair P: [vmcnt(6)] [barrier]
// [2 rows x 48 MFMA] [barrier] [stage 2 rows]. Direct f32x4 stores.
__device__ __forceinline__ void conv_body(int cblk, const unsigned short* __restrict__ xT,
                                          const unsigned short* __restrict__ wT,
                                          const float* __restrict__ bb,
                                          const float* __restrict__ bng,
                                          const float* __restrict__ bnb,
                                          const float* __restrict__ bnm,
                                          const float* __restrict__ bnv,
                                          const unsigned short* __restrict__ zbuf,
                                          float* __restrict__ out, char* smemc) {
  int nb = ((cblk & 7) << 8) | (cblk >> 3);  // XCD swizzle (2048 % 8 == 0)
  int ocb = nb & 1, y = (nb >> 1) & 127, b = nb >> 8;
  int lane = threadIdx.x & 63, wid = threadIdx.x >> 6;
  int m_l = lane & 15, kgrp = lane >> 4;

  unsigned short* xs = (unsigned short*)smemc;  // ring: 4 x 8320B row slots
  const char* zc = (const char*)zbuf;

  // per-thread staging constants: wave w covers granules [w*130, w*130+130)
  int g0 = wid * 130 + lane, g1 = g0 + 64, g2 = wid * 130 + 128 + lane;  // g2: lane<2
  int px0_ = g0 >> 2, k0_ = g0 & 3, s0_ = k0_ ^ ((px0_ >> 1) & 3), gx0 = px0_ - 1;
  int px1_ = g1 >> 2, k1_ = g1 & 3, s1_ = k1_ ^ ((px1_ >> 1) & 3), gx1 = px1_ - 1;
  int px2_ = g2 >> 2, k2_ = g2 & 3, s2_ = k2_ ^ ((px2_ >> 1) & 3), gx2 = px2_ - 1;
  bool ok0 = (unsigned)gx0 < 128u, ok1 = (unsigned)gx1 < 128u, ok2 = (unsigned)gx2 < 128u;
  int off0 = gx0 * 512 + s0_ * 16, off1 = gx1 * 512 + s1_ * 16, off2 = gx2 * 512 + s2_ * 16;
  int d0 = (wid * 130) * 16, d1 = d0 + 1024, d2 = d0 + 2048;  // wave-uniform LDS bases

#define STAGE_ROW(slotB_, cbn_, khn_)                                                       \
  do {                                                                                      \
    int gy_ = y + (khn_)-1;                                                                 \
    bool gyok_ = ((unsigned)gy_ < 128u);                                                    \
    const char* rb_ =                                                                       \
        (const char*)xT + (((size_t)b << 14) + (size_t)(gy_ & 127) * 128) * 512 + (cbn_)*64;\
    gload16((gyok_ && ok0) ? rb_ + off0 : zc, smemc + (slotB_) + d0);                       \
    gload16((gyok_ && ok1) ? rb_ + off1 : zc, smemc + (slotB_) + d1);                       \
    if (lane < 2) gload16((gyok_ && ok2) ? rb_ + off2 : zc, smemc + (slotB_) + d2);         \
  } while (0)

  f32x4 acc[8][2];
#pragma unroll
  for (int mt = 0; mt < 8; ++mt)
#pragma unroll
    for (int nt = 0; nt < 2; ++nt) acc[mt][nt] = (f32x4)0.f;

  // prologue: stage rows 0..3 (row r -> cb=r/3, kh=r%3, slot r&3)
  STAGE_ROW(0, 0, 0);
  STAGE_ROW(8320, 0, 1);
  STAGE_ROW(16640, 0, 2);
  STAGE_ROW(24960, 1, 0);

  // per-thread bfrag base (ushorts); wave owns oc band [ocb*128 + wid*32, +32)
  int oc0 = ocb * 128 + wid * 32;
  const unsigned short* wTb = wT + ((size_t)(oc0 + m_l) * 32 + kgrp * 8);
  int khn = 1, cbn = 1;  // next row to stage = 4 -> cb1,kh1

#pragma unroll 1
  for (int P = 0; P < 12; ++P) {
    if (P < 11) {
      asm volatile("s_waitcnt vmcnt(6)" ::: "memory");  // rows 2P,2P+1 landed
    } else {
      asm volatile("s_waitcnt vmcnt(0)" ::: "memory");
    }
    __builtin_amdgcn_s_barrier();
    asm volatile("" ::: "memory");
#pragma unroll
    for (int half = 0; half < 2; ++half) {
      int R = 2 * P + half;
      const unsigned short* xb = xs + (R & 3) * 4160;
#pragma unroll
      for (int kw = 0; kw < 3; ++kw) {
        bf16x8 bfrag[2];
        const unsigned short* wb = wTb + (size_t)(R * 3 + kw) * 8192;
#pragma unroll
        for (int nt = 0; nt < 2; ++nt) bfrag[nt] = *(const bf16x8*)(wb + nt * 512);
#pragma unroll
        for (int mt = 0; mt < 8; ++mt) {
          int apx = mt * 16 + m_l + kw;
          int kk = kgrp ^ ((apx >> 1) & 3);
          bf16x8 af =
              *(__attribute__((address_space(3))) bf16x8*)(&xb[apx * 32 + kk * 8]);
#pragma unroll
          for (int nt = 0; nt < 2; ++nt)
            acc[mt][nt] =
                __builtin_amdgcn_mfma_f32_16x16x32_bf16(af, bfrag[nt], acc[mt][nt], 0, 0, 0);
        }
      }
    }
    __builtin_amdgcn_s_barrier();  // slots (2P)&3, (2P+1)&3 free
    asm volatile("" ::: "memory");
    if (P < 10) {
      STAGE_ROW((size_t)((2 * P + 4) & 3) * 8320, cbn, khn);
      ++khn;
      if (khn == 3) { khn = 0; ++cbn; }
      STAGE_ROW((size_t)((2 * P + 5) & 3) * 8320, cbn, khn);
      ++khn;
      if (khn == 3) { khn = 0; ++cbn; }
    }
  }
#undef STAGE_ROW

  // epilogue: direct stores — wave owns oc rows [oc0, oc0+32), all 128 px.
  float scale2[2], bias2[2];
#pragma unroll
  for (int nt = 0; nt < 2; ++nt) {
    int oc = oc0 + nt * 16 + m_l;
    float s = bng[oc] * rsqrtf(bnv[oc] + EPS_);
    scale2[nt] = s;
    bias2[nt] = bnb[oc] + (bb[oc] - bnm[oc]) * s;
  }
#pragma unroll
  for (int nt = 0; nt < 2; ++nt) {
    size_t obase = (((size_t)(b * 256 + oc0 + nt * 16 + m_l)) << 14) + y * 128 + kgrp * 4;
#pragma unroll
    for (int mt = 0; mt < 8; ++mt) {
      f32x4 v = acc[mt][nt];
      float o4[4];
#pragma unroll
      for (int r = 0; r < 4; ++r) {
        float hv = v[r] * scale2[nt] + bias2[nt];
        o4[r] = hv * sigmoidf_(hv);
      }
      *(f32x4*)(out + obase + mt * 16) = (f32x4){o4[0], o4[1], o4[2], o4[3]};
    }
  }
}

// ---------------------------------------------------------------- fused dispatch (R10 config)
__global__ __launch_bounds__(256, 4) void fused_kernel(
    int kgN, const unsigned short* __restrict__ xT, const unsigned short* __restrict__ wT,
    const float* __restrict__ w1f, const float* __restrict__ b1f, const float* __restrict__ w2t,
    const float* __restrict__ b2, float* __restrict__ kern, const float* __restrict__ bb,
    const float* __restrict__ bng, const float* __restrict__ bnb, const float* __restrict__ bnm,
    const float* __restrict__ bnv, const unsigned short* __restrict__ zbuf,
    float* __restrict__ out) {
  __shared__ char smem[33280];  // conv ring (33,280B); kernelgen uses first 25,920B
  int blk = (int)blockIdx.x;
  if (blk < kgN) {
    kernelgen_body(blk, xT, w1f, b1f, w2t, b2, kern, smem);
  } else {
    conv_body(blk - kgN, xT, wT, bb, bng, bnb, bnm, bnv, zbuf, out, smem);
  }
}

// ---------------------------------------------------------------- CARAFE + blend (RMW on out)
// grid 4096; XCD-TILE CLUSTERING: a tile's 16 ch-group blocks land on the SAME XCD
// (xcd = blk&7; ocg = (blk>>3)&15; tile = (blk>>7)*8 + xcd) -> the 16x re-read of the
// tile's kern 25-vector block and the out tile RMW become L2-local instead of
// scattering across 8 XCDs. Inner tap loop on f32x2 ch-pairs -> v_pk_fma_f32.
__global__ __launch_bounds__(256) void carafe_blend_kernel(
    const unsigned short* __restrict__ xT, const float* __restrict__ kern,
    const float* __restrict__ gq, float* __restrict__ out) {
  int blk = blockIdx.x;
  int xcd = blk & 7, r = blk >> 3;
  int ocg = r & 15;
  int tile = (r >> 4) * 8 + xcd;  // 0..255
  int b = tile >> 5, rem = tile & 31;
  int by = rem >> 3, bx = rem & 7;
  __shared__ unsigned short xc[720 * 16];  // [36x20 px][16 ch]
  for (int i = threadIdx.x; i < 1440; i += 256) {
    int half = i & 1, p = i >> 1;
    int py = p / 20, pxx = p - py * 20;
    int yy = by * 32 + py - 2, xx = bx * 16 + pxx - 2;
    yy = yy < 0 ? -yy : (yy > 127 ? 254 - yy : yy);
    xx = xx < 0 ? -xx : (xx > 127 ? 254 - xx : xx);
    *(lds_u16x8*)(&xc[p * 16 + half * 8]) =
        *(const u16x8*)(xT + (((size_t)(b << 14)) + yy * 128 + xx) * 256 + ocg * 16 + half * 8);
  }
  __syncthreads();
  int lx = threadIdx.x & 15, y0 = (threadIdx.x >> 4) * 2;
  float gv = gq[b];
  int gy0 = by * 32 + y0, gx = bx * 16 + lx;
  float kv0[25], kv1[25];
  size_t kb = (((size_t)b * 25) << 14) + gy0 * 128 + gx;
#pragma unroll
  for (int n = 0; n < 25; ++n) {
    kv0[n] = kern[kb + ((size_t)n << 14)];
    kv1[n] = kern[kb + ((size_t)n << 14) + 128];
  }
  f32x2 car0[8], car1[8];
#pragma unroll
  for (int c = 0; c < 8; ++c) { car0[c] = (f32x2)0.f; car1[c] = (f32x2)0.f; }
#pragma unroll
  for (int n = 0; n < 25; ++n) {
    int ki = n / 5, kj = n - ki * 5;
    int p0 = (y0 + ki) * 20 + lx + kj;
    f32x2 kvv0 = (f32x2){kv0[n], kv0[n]}, kvv1 = (f32x2){kv1[n], kv1[n]};
    union { u16x8 s8; unsigned int u[4]; } a0, a1, b0, b1;
    a0.s8 = *(lds_u16x8*)(&xc[p0 * 16]);
    a1.s8 = *(lds_u16x8*)(&xc[p0 * 16 + 8]);
    b0.s8 = *(lds_u16x8*)(&xc[(p0 + 20) * 16]);
    b1.s8 = *(lds_u16x8*)(&xc[(p0 + 20) * 16 + 8]);
#pragma unroll
    for (int j = 0; j < 4; ++j) {
      f32x2 f0 = (f32x2){__uint_as_float(a0.u[j] << 16), __uint_as_float(a0.u[j] & 0xffff0000u)};
      f32x2 f1 = (f32x2){__uint_as_float(a1.u[j] << 16), __uint_as_float(a1.u[j] & 0xffff0000u)};
      f32x2 g0 = (f32x2){__uint_as_float(b0.u[j] << 16), __uint_as_float(b0.u[j] & 0xffff0000u)};
      f32x2 g1 = (f32x2){__uint_as_float(b1.u[j] << 16), __uint_as_float(b1.u[j] & 0xffff0000u)};
      car0[j] = pkfma_(f0, kvv0, car0[j]);
      car0[4 + j] = pkfma_(f1, kvv0, car0[4 + j]);
      car1[j] = pkfma_(g0, kvv1, car1[j]);
      car1[4 + j] = pkfma_(g1, kvv1, car1[4 + j]);
    }
  }
#pragma unroll
  for (int j = 0; j < 8; ++j) {
    // pair j covers channels 2j, 2j+1
    size_t ob0 = (((size_t)(b * 256 + ocg * 16 + 2 * j)) << 14) + gy0 * 128 + gx;
    size_t ob1 = ob0 + 16384;
    float s00 = out[ob0], s01 = out[ob0 + 128];
    float s10 = out[ob1], s11 = out[ob1 + 128];
    out[ob0] = fmaf(gv, car0[j].x - s00, s00);
    out[ob0 + 128] = fmaf(gv, car1[j].x - s01, s01);
    out[ob1] = fmaf(gv, car0[j].y - s10, s10);
    out[ob1 + 128] = fmaf(gv, car1[j].y - s11, s11);
  }
}

// ---------------------------------------------------------------- launcher
extern "C" void kernel_launch(void* const* d_in, const int* in_sizes, int n_in,
                              void* d_out, int out_size, void* d_ws, size_t ws_size,
                              hipStream_t stream) {
  const float* x      = (const float*)d_in[0];
  const float* ke_w1  = (const float*)d_in[1];
  const float* ke_b1  = (const float*)d_in[2];
  const float* ke_bng = (const float*)d_in[3];
  const float* ke_bnb = (const float*)d_in[4];
  const float* ke_bnm = (const float*)d_in[5];
  const float* ke_bnv = (const float*)d_in[6];
  const float* ke_w2  = (const float*)d_in[7];
  const float* ke_b2  = (const float*)d_in[8];
  const float* bs_w   = (const float*)d_in[9];
  const float* bs_b   = (const float*)d_in[10];
  const float* bs_bng = (const float*)d_in[11];
  const float* bs_bnb = (const float*)d_in[12];
  const float* bs_bnm = (const float*)d_in[13];
  const float* bs_bnv = (const float*)d_in[14];
  const float* g_w    = (const float*)d_in[15];
  const float* g_b    = (const float*)d_in[16];
  float* outp = (float*)d_out;

  char* ws = (char*)d_ws;
  float* kern        = (float*)(ws);                      // 13,107,200 B
  float* partial     = (float*)(ws + 13107200);           // 8,192 B
  float* gout        = (float*)(ws + 13115392);           // bytes 0-31 of 256B slot
  float* zbuff       = (float*)(ws + 13115392 + 128);     // 64B zero pad
  unsigned short* wT = (unsigned short*)(ws + 13115648);  // 1,179,648 B
  unsigned short* xT = (unsigned short*)(ws + 14295296);  // 67,108,864 B -> 81,404,160 total

  // kprep tables (103,424 B): prefer ws tail (enables fused launch: conv writes out
  // concurrently, so tables must NOT alias d_out). If ws is too small, fall back to
  // dead d_out space + serial launches.
  const size_t USED = 81404160;
  bool bigws = ws_size >= USED + 131072;
  float *w1f, *b1f, *w2t;
  if (bigws) {
    w1f = (float*)(ws + USED);            // 73,728 B
    b1f = (float*)(ws + USED + 73728);    //  1,024 B
    w2t = (float*)(ws + USED + 74752);    // 28,672 B
  } else {
    w1f = (float*)((char*)d_out + 52428800);
    b1f = (float*)((char*)d_out + 52502528);
    w2t = (float*)((char*)d_out + 52503552);
  }

  hipMemsetAsync(partial, 0, 2048 * sizeof(float), stream);  // GAP accumulators
  prep_kernel<<<2376, 256, 0, stream>>>(bs_w, wT, ke_w1, ke_b1, ke_bng, ke_bnb, ke_bnm,
                                        ke_bnv, ke_w2, w1f, b1f, w2t, zbuff);
  transpose_kernel<<<2048, 256, 0, stream>>>(x, xT, partial);
  gate_kernel<<<8, 256, 0, stream>>>(partial, g_w, g_b, gout);

  if (bigws) {
    // fused: 512 kernelgen blocks (first, all co-resident) + 2048 conv blocks
    fused_kernel<<<2560, 256, 0, stream>>>(512, xT, wT, w1f, b1f, w2t, ke_b2, kern, bs_b,
                                           bs_bng, bs_bnb, bs_bnm, bs_bnv,
                                           (const unsigned short*)zbuff, outp);
  } else {
    // serial fallback: tables live in d_out (dead until conv runs after kernelgen)
    fused_kernel<<<512, 256, 0, stream>>>(512, xT, wT, w1f, b1f, w2t, ke_b2, kern, bs_b,
                                          bs_bng, bs_bnb, bs_bnm, bs_bnv,
                                          (const unsigned short*)zbuff, outp);
    fused_kernel<<<2048, 256, 0, stream>>>(0, xT, wT, w1f, b1f, w2t, ke_b2, kern, bs_b,
                                           bs_bng, bs_bnb, bs_bnm, bs_bnv,
                                           (const unsigned short*)zbuff, outp);
  }
  carafe_blend_kernel<<<4096, 256, 0, stream>>>(xT, kern, gout, outp);
}

// Round 14
// 520.941 us; speedup vs baseline: 1.4465x; 1.2645x over previous
//
#include <hip/hip_runtime.h>

#define EPS_ 1e-5f

typedef __attribute__((ext_vector_type(8))) short bf16x8;
typedef __attribute__((ext_vector_type(8))) unsigned short u16x8;
typedef __attribute__((ext_vector_type(4))) float f32x4;
typedef __attribute__((ext_vector_type(2))) float f32x2;
typedef __attribute__((ext_vector_type(2))) unsigned int u32x2;
typedef __attribute__((address_space(3))) u16x8 lds_u16x8;
typedef __attribute__((address_space(3))) f32x4 lds_f32x4;
typedef __attribute__((address_space(3))) u32x2 lds_u32x2;
typedef __attribute__((address_space(3))) bf16x8 lds_bf16x8;

__device__ __forceinline__ float sigmoidf_(float v) { return 1.f / (1.f + __expf(-v)); }

__device__ __forceinline__ unsigned short f2bf(float f) {
  unsigned int u = __float_as_uint(f);
  u += 0x7fff + ((u >> 16) & 1);  // RNE
  return (unsigned short)(u >> 16);
}

__device__ __forceinline__ void cvt8_(u16x8 v, float* f) {
  union { u16x8 s; unsigned int u[4]; } uu;
  uu.s = v;
#pragma unroll
  for (int j = 0; j < 4; ++j) {
    f[2 * j] = __uint_as_float(uu.u[j] << 16);
    f[2 * j + 1] = __uint_as_float(uu.u[j] & 0xffff0000u);
  }
}

// pk-fma: float2 fused multiply-add -> v_pk_fma_f32 on gfx950
__device__ __forceinline__ f32x2 pkfma_(f32x2 a, f32x2 b, f32x2 c) {
#if __has_builtin(__builtin_elementwise_fma)
  return __builtin_elementwise_fma(a, b, c);
#else
  return (f32x2){fmaf(a.x, b.x, c.x), fmaf(a.y, b.y, c.y)};
#endif
}

// async global->LDS, 16B per lane; LDS dest is wave-uniform base + lane*16
__device__ __forceinline__ void gload16(const void* g, void* l) {
  __builtin_amdgcn_global_load_lds((const __attribute__((address_space(1))) unsigned int*)(g),
                                   (__attribute__((address_space(3))) unsigned int*)(l), 16, 0, 0);
}

// ---------------------------------------------------------------- gate stage 2
__global__ void gate_kernel(const float* __restrict__ partial, const float* __restrict__ gw,
                            const float* __restrict__ gb, float* __restrict__ gout) {
  int b = blockIdx.x, t = threadIdx.x;
  float s = partial[b * 256 + t] * gw[t];
#pragma unroll
  for (int off = 32; off; off >>= 1) s += __shfl_down(s, off, 64);
  __shared__ float red[4];
  if ((t & 63) == 0) red[t >> 6] = s;
  __syncthreads();
  if (t == 0) {
    float tot = (red[0] + red[1]) + (red[2] + red[3]);
    gout[b] = sigmoidf_(tot * (1.f / 16384.f) + gb[0]);
  }
}

// ---------------------------------------------------------------- merged prep
// [0,2304): wtrans. [2304,2464): w1b MFMA-fragment table for grouped conv
// (per group-pair gp: M=16 oc, K=160 (9 taps x 16 ic, zero-padded block-diagonal)).
// [2464,2496): w2b fragment table for the 1x1 (n=25 pad 32, K=256).
// 2496: b1f (BN-folded bias), b2p (b2 padded with -1e30), zbuff.
__global__ void prep_kernel(const float* __restrict__ w, unsigned short* __restrict__ wT,
                            const float* __restrict__ w1, const float* __restrict__ b1,
                            const float* __restrict__ bng, const float* __restrict__ bnb,
                            const float* __restrict__ bnm, const float* __restrict__ bnv,
                            const float* __restrict__ w2, const float* __restrict__ b2,
                            unsigned short* __restrict__ w1b, unsigned short* __restrict__ w2b,
                            float* __restrict__ b1f, float* __restrict__ b2p,
                            float* __restrict__ zb) {
  int blk = blockIdx.x;
  if (blk < 2304) {
    int n = blk * 256 + threadIdx.x;  // 589824
    int c = n & 31, oc = (n >> 5) & 255, t9 = n >> 13;
    int cb = t9 / 9, tap = t9 - cb * 9;
    wT[n] = f2bf(w[(oc * 256 + cb * 32 + c) * 9 + tap]);
  } else if (blk < 2464) {
    int n = (blk - 2304) * 256 + threadIdx.x;  // [0, 40960)
    int j = n & 7, r1 = n >> 3;
    int lane = r1 & 63, r2 = r1 >> 6;  // r2 in [0,80)
    int step = r2 % 5, gp = r2 / 5;
    int oc_l = lane & 15, kg2 = lane >> 4;
    int k = step * 32 + kg2 * 8 + j;
    int tap = k >> 4, icp = k & 15;
    int c = gp * 16 + oc_l;
    bool valid = (tap < 9) && ((icp >> 3) == (oc_l >> 3));
    float s = bng[c] * rsqrtf(bnv[c] + EPS_);
    w1b[n] = f2bf(valid ? w1[c * 72 + (icp & 7) * 9 + tap] * s : 0.f);
  } else if (blk < 2496) {
    int n = (blk - 2464) * 256 + threadIdx.x;  // [0, 8192)
    int j = n & 7, r1 = n >> 3;
    int lane = r1 & 63, r2 = r1 >> 6;  // [0,16)
    int ntile = r2 & 1, rnd = r2 >> 1;
    int nn = ntile * 16 + (lane & 15);
    int c = rnd * 32 + (lane >> 4) * 8 + j;
    w2b[n] = f2bf((nn < 25) ? w2[nn * 256 + c] : 0.f);
  } else {
    int n = threadIdx.x;
    if (n < 16) zb[n] = 0.f;
    if (n < 32) b2p[n] = (n < 25) ? b2[n] : -1e30f;
    if (n < 256) {
      float s = bng[n] * rsqrtf(bnv[n] + EPS_);
      b1f[n] = (b1[n] - bnm[n]) * s + bnb[n];
    }
  }
}

// ---------------------------------------------------------------- x fp32 NCHW -> xT bf16 NHWC
// + fused GAP partial sums (atomicAdd into partial[b*256+ch]; saves a full x re-read).
__global__ __launch_bounds__(256) void transpose_kernel(const float* __restrict__ x,
                                                        unsigned short* __restrict__ xT,
                                                        float* __restrict__ partial) {
  int blk = blockIdx.x;
  int tile = blk & 255, b = blk >> 8;
  int px0 = tile * 64;
  __shared__ unsigned int tr[64 * 130];  // [px][128 ch-pair words + 2 pad]
  for (int i = threadIdx.x; i < 1024; i += 256) {
    int ch2 = i >> 3, pc = i & 7;
    const float* p0 = x + (((size_t)b * 256 + ch2 * 2) << 14) + px0 + pc * 8;
    const float4* a4 = (const float4*)p0;
    const float4* b4 = (const float4*)(p0 + 16384);
    float4 a0 = a4[0], a1 = a4[1], b0 = b4[0], b1 = b4[1];
    float fa[8] = {a0.x, a0.y, a0.z, a0.w, a1.x, a1.y, a1.z, a1.w};
    float fb[8] = {b0.x, b0.y, b0.z, b0.w, b1.x, b1.y, b1.z, b1.w};
    float sa = 0.f, sb = 0.f;
#pragma unroll
    for (int j = 0; j < 8; ++j) {
      sa += fa[j];
      sb += fb[j];
      unsigned int w = (unsigned int)f2bf(fa[j]) | ((unsigned int)f2bf(fb[j]) << 16);
      tr[(pc * 8 + j) * 130 + ch2] = w;
    }
    sa += __shfl_down(sa, 4, 8); sa += __shfl_down(sa, 2, 8); sa += __shfl_down(sa, 1, 8);
    sb += __shfl_down(sb, 4, 8); sb += __shfl_down(sb, 2, 8); sb += __shfl_down(sb, 1, 8);
    if ((threadIdx.x & 7) == 0) {
      atomicAdd(&partial[(b << 8) + ch2 * 2], sa);
      atomicAdd(&partial[(b << 8) + ch2 * 2 + 1], sb);
    }
  }
  __syncthreads();
  for (int i = threadIdx.x; i < 2048; i += 256) {
    int px = i >> 5, kc = i & 31;
    uint4 v = *(uint4*)&tr[px * 130 + kc * 4];
    *(uint4*)(xT + ((((size_t)b << 14)) + px0 + px) * 256 + kc * 8) = v;
  }
}

// ---------------------------------------------------------------- kernelgen via MFMA
// Per block: 16x16 px tile, 4 waves, wave w owns tile-rows m = 4w..4w+3.
// Per group-pair gp (16 rounds): stage halo [18x18 px][16 ch] (linear, gload16,
// zbuff redirect); first MFMA (swapped: A=w1b frag M=oc16, B=x frag N=px16,
// K=160 in 5 steps; taps zero-padded in w1b) -> C rows=oc: +b1f, SiLU, pack bf16,
// ds_write_b64 into hbuf[256 px][40 ch-pad]. Every 2 gp: second MFMA
// (A=w2b frag M=n, B=h frag N=px, K=32) accumulates acc2[mloc][ntile].
// Epilogue: +b2p, softmax over n via 2x shfl_xor (px = lane&15), coalesced stores.
// LDS: halo 10,368 + hbuf 20,480 = 30,848 <= conv's 33,280 (residency unchanged).
__device__ __forceinline__ void kernelgen_body(
    int kblk, const unsigned short* __restrict__ xT, const unsigned short* __restrict__ w1b,
    const unsigned short* __restrict__ w2b, const float* __restrict__ b1f,
    const float* __restrict__ b2p, const unsigned short* __restrict__ zbuf,
    float* __restrict__ kern, char* smemc) {
  char* hbufc = smemc + 10368;
  int t = kblk & 63, b = kblk >> 6;
  int px0 = (t & 7) * 16, py0 = (t >> 3) * 16;
  int lane = threadIdx.x & 63, wid = threadIdx.x >> 6;
  int nx = lane & 15, kgrp = lane >> 4;
  const char* zc = (const char*)zbuf;

  // staging descriptors: wave stages halo granules [wid*162, +162); g = p*2 + half
  size_t soff[3];
  bool okk[3];
#pragma unroll
  for (int i = 0; i < 3; ++i) {
    int g = wid * 162 + i * 64 + lane;
    int p = g >> 1, half = g & 1;
    int hy = p / 18, hx = p - hy * 18;
    int gy = py0 + hy - 1, gx = px0 + hx - 1;
    okk[i] = ((unsigned)gy < 128u) && ((unsigned)gx < 128u);
    soff[i] = (size_t)((gy & 127) * 128 + (gx & 127)) * 512 + half * 16;
  }
  const char* imgbase = (const char*)xT + (((size_t)b << 14) * 512);
  int dstb = wid * 2592;

  // x-frag address constants: per K-step s, tap = min(2s + (kgrp>>1), 8)
  int aoff[5];
  int base_t = nx * 32 + (kgrp & 1) * 16;
#pragma unroll
  for (int s = 0; s < 5; ++s) {
    int tap = 2 * s + (kgrp >> 1);
    if (tap > 8) tap = 8;
    int dy = tap / 3, dx = tap - dy * 3;
    aoff[s] = dy * 576 + dx * 32 + base_t;
  }

  f32x4 acc2[4][2];
#pragma unroll
  for (int ml = 0; ml < 4; ++ml)
#pragma unroll
    for (int nt = 0; nt < 2; ++nt) acc2[ml][nt] = (f32x4)0.f;

#pragma unroll 1
  for (int gp = 0; gp < 16; ++gp) {
    __syncthreads();  // halo reads of prev round complete
    gload16(okk[0] ? imgbase + soff[0] + gp * 32 : zc, smemc + dstb);
    gload16(okk[1] ? imgbase + soff[1] + gp * 32 : zc, smemc + dstb + 1024);
    if (lane < 34) gload16(okk[2] ? imgbase + soff[2] + gp * 32 : zc, smemc + dstb + 2048);
    asm volatile("s_waitcnt vmcnt(0)" ::: "memory");
    __builtin_amdgcn_s_barrier();
    asm volatile("" ::: "memory");

    // weight frags + bias for this group-pair (wave-uniform-ish loads, L2-hot)
    bf16x8 wf[5];
    const unsigned short* wp = w1b + ((size_t)(gp * 5) * 64 + lane) * 8;
#pragma unroll
    for (int s = 0; s < 5; ++s) wf[s] = *(const bf16x8*)(wp + s * 512);
    f32x4 bias = *(const f32x4*)(b1f + gp * 16 + kgrp * 4);

#pragma unroll
    for (int ml = 0; ml < 4; ++ml) {
      int m = wid * 4 + ml;
      f32x4 cf = (f32x4)0.f;
#pragma unroll
      for (int s = 0; s < 5; ++s) {
        bf16x8 xf = *(lds_bf16x8*)(smemc + m * 576 + aoff[s]);
        cf = __builtin_amdgcn_mfma_f32_16x16x32_bf16(wf[s], xf, cf, 0, 0, 0);
      }
      // C: col px = nx, rows oc = kgrp*4 + r. bias + SiLU + bf16 pack -> hbuf b64.
      unsigned short us[4];
#pragma unroll
      for (int r = 0; r < 4; ++r) {
        float hv = cf[r] + bias[r];
        us[r] = f2bf(hv * sigmoidf_(hv));
      }
      unsigned int lo = (unsigned int)us[0] | ((unsigned int)us[1] << 16);
      unsigned int hi = (unsigned int)us[2] | ((unsigned int)us[3] << 16);
      *(lds_u32x2*)(hbufc + (m * 16 + nx) * 80 + (gp & 1) * 32 + kgrp * 8) = (u32x2){lo, hi};
    }

    if (gp & 1) {  // 32-ch window complete -> 1x1 MFMA chunk
      int rnd = gp >> 1;
      const unsigned short* w2p = w2b + ((size_t)(rnd * 2) * 64 + lane) * 8;
      bf16x8 w2f0 = *(const bf16x8*)(w2p);
      bf16x8 w2f1 = *(const bf16x8*)(w2p + 512);
#pragma unroll
      for (int ml = 0; ml < 4; ++ml) {
        int m = wid * 4 + ml;
        bf16x8 hf = *(lds_bf16x8*)(hbufc + (m * 16 + nx) * 80 + kgrp * 16);
        acc2[ml][0] = __builtin_amdgcn_mfma_f32_16x16x32_bf16(w2f0, hf, acc2[ml][0], 0, 0, 0);
        acc2[ml][1] = __builtin_amdgcn_mfma_f32_16x16x32_bf16(w2f1, hf, acc2[ml][1], 0, 0, 0);
      }
    }
  }

  // softmax over n per px (px = nx; n = nt*16 + kgrp*4 + r across lanes nx+16k)
  f32x4 blo = *(const f32x4*)(b2p + kgrp * 4);
  f32x4 bhi = *(const f32x4*)(b2p + 16 + kgrp * 4);
#pragma unroll
  for (int ml = 0; ml < 4; ++ml) {
    int m = wid * 4 + ml;
    float v[8];
#pragma unroll
    for (int r = 0; r < 4; ++r) {
      v[r] = acc2[ml][0][r] + blo[r];
      v[4 + r] = acc2[ml][1][r] + bhi[r];
    }
    float mx = v[0];
#pragma unroll
    for (int i = 1; i < 8; ++i) mx = fmaxf(mx, v[i]);
    mx = fmaxf(mx, __shfl_xor(mx, 16, 64));
    mx = fmaxf(mx, __shfl_xor(mx, 32, 64));
    float sum = 0.f;
#pragma unroll
    for (int i = 0; i < 8; ++i) { v[i] = __expf(v[i] - mx); sum += v[i]; }
    sum += __shfl_xor(sum, 16, 64);
    sum += __shfl_xor(sum, 32, 64);
    float inv = 1.f / sum;
    size_t base = (((size_t)b * 25) << 14) + (size_t)(py0 + m) * 128 + px0 + nx;
#pragma unroll
    for (int nt = 0; nt < 2; ++nt)
#pragma unroll
      for (int r = 0; r < 4; ++r) {
        int n = nt * 16 + kgrp * 4 + r;
        if (n < 25) kern[base + ((size_t)n << 14)] = v[nt * 4 + r] * inv;
      }
  }
}

// conv body (R10 config): M=128 px x N=128 oc; K = 24 rows x 32 ch. WAVE = 128px x
// 32oc (mt=8, nt=2). ROW-PAIR RING-4 PIPELINE: per pair P: [vmcnt(6)] [barrier]
// [2 rows x 48 MFMA] [barrier] [stage 2 rows]. Direct f32x4 stores.
__device__ __forceinline__ void conv_body(int cblk, const unsigned short* __restrict__ xT,
                                          const unsigned short* __restrict__ wT,
                                          const float* __restrict__ bb,
                                          const float* __restrict__ bng,
                                          const float* __restrict__ bnb,
                                          const float* __restrict__ bnm,
                                          const float* __restrict__ bnv,
                                          const unsigned short* __restrict__ zbuf,
                                          float* __restrict__ out, char* smemc) {
  int nb = ((cblk & 7) << 8) | (cblk >> 3);  // XCD swizzle (2048 % 8 == 0)
  int ocb = nb & 1, y = (nb >> 1) & 127, b = nb >> 8;
  int lane = threadIdx.x & 63, wid = threadIdx.x >> 6;
  int m_l = lane & 15, kgrp = lane >> 4;

  unsigned short* xs = (unsigned short*)smemc;  // ring: 4 x 8320B row slots
  const char* zc = (const char*)zbuf;

  int g0 = wid * 130 + lane, g1 = g0 + 64, g2 = wid * 130 + 128 + lane;  // g2: lane<2
  int px0_ = g0 >> 2, k0_ = g0 & 3, s0_ = k0_ ^ ((px0_ >> 1) & 3), gx0 = px0_ - 1;
  int px1_ = g1 >> 2, k1_ = g1 & 3, s1_ = k1_ ^ ((px1_ >> 1) & 3), gx1 = px1_ - 1;
  int px2_ = g2 >> 2, k2_ = g2 & 3, s2_ = k2_ ^ ((px2_ >> 1) & 3), gx2 = px2_ - 1;
  bool ok0 = (unsigned)gx0 < 128u, ok1 = (unsigned)gx1 < 128u, ok2 = (unsigned)gx2 < 128u;
  int off0 = gx0 * 512 + s0_ * 16, off1 = gx1 * 512 + s1_ * 16, off2 = gx2 * 512 + s2_ * 16;
  int d0 = (wid * 130) * 16, d1 = d0 + 1024, d2 = d0 + 2048;

#define STAGE_ROW(slotB_, cbn_, khn_)                                                       \
  do {                                                                                      \
    int gy_ = y + (khn_)-1;                                                                 \
    bool gyok_ = ((unsigned)gy_ < 128u);                                                    \
    const char* rb_ =                                                                       \
        (const char*)xT + (((size_t)b << 14) + (size_t)(gy_ & 127) * 128) * 512 + (cbn_)*64;\
    gload16((gyok_ && ok0) ? rb_ + off0 : zc, smemc + (slotB_) + d0);                       \
    gload16((gyok_ && ok1) ? rb_ + off1 : zc, smemc + (slotB_) + d1);                       \
    if (lane < 2) gload16((gyok_ && ok2) ? rb_ + off2 : zc, smemc + (slotB_) + d2);         \
  } while (0)

  f32x4 acc[8][2];
#pragma unroll
  for (int mt = 0; mt < 8; ++mt)
#pragma unroll
    for (int nt = 0; nt < 2; ++nt) acc[mt][nt] = (f32x4)0.f;

  STAGE_ROW(0, 0, 0);
  STAGE_ROW(8320, 0, 1);
  STAGE_ROW(16640, 0, 2);
  STAGE_ROW(24960, 1, 0);

  int oc0 = ocb * 128 + wid * 32;
  const unsigned short* wTb = wT + ((size_t)(oc0 + m_l) * 32 + kgrp * 8);
  int khn = 1, cbn = 1;

#pragma unroll 1
  for (int P = 0; P < 12; ++P) {
    if (P < 11) {
      asm volatile("s_waitcnt vmcnt(6)" ::: "memory");
    } else {
      asm volatile("s_waitcnt vmcnt(0)" ::: "memory");
    }
    __builtin_amdgcn_s_barrier();
    asm volatile("" ::: "memory");
#pragma unroll
    for (int half = 0; half < 2; ++half) {
      int R = 2 * P + half;
      const unsigned short* xb = xs + (R & 3) * 4160;
#pragma unroll
      for (int kw = 0; kw < 3; ++kw) {
        bf16x8 bfrag[2];
        const unsigned short* wb = wTb + (size_t)(R * 3 + kw) * 8192;
#pragma unroll
        for (int nt = 0; nt < 2; ++nt) bfrag[nt] = *(const bf16x8*)(wb + nt * 512);
#pragma unroll
        for (int mt = 0; mt < 8; ++mt) {
          int apx = mt * 16 + m_l + kw;
          int kk = kgrp ^ ((apx >> 1) & 3);
          bf16x8 af =
              *(__attribute__((address_space(3))) bf16x8*)(&xb[apx * 32 + kk * 8]);
#pragma unroll
          for (int nt = 0; nt < 2; ++nt)
            acc[mt][nt] =
                __builtin_amdgcn_mfma_f32_16x16x32_bf16(af, bfrag[nt], acc[mt][nt], 0, 0, 0);
        }
      }
    }
    __builtin_amdgcn_s_barrier();
    asm volatile("" ::: "memory");
    if (P < 10) {
      STAGE_ROW((size_t)((2 * P + 4) & 3) * 8320, cbn, khn);
      ++khn;
      if (khn == 3) { khn = 0; ++cbn; }
      STAGE_ROW((size_t)((2 * P + 5) & 3) * 8320, cbn, khn);
      ++khn;
      if (khn == 3) { khn = 0; ++cbn; }
    }
  }
#undef STAGE_ROW

  float scale2[2], bias2[2];
#pragma unroll
  for (int nt = 0; nt < 2; ++nt) {
    int oc = oc0 + nt * 16 + m_l;
    float s = bng[oc] * rsqrtf(bnv[oc] + EPS_);
    scale2[nt] = s;
    bias2[nt] = bnb[oc] + (bb[oc] - bnm[oc]) * s;
  }
#pragma unroll
  for (int nt = 0; nt < 2; ++nt) {
    size_t obase = (((size_t)(b * 256 + oc0 + nt * 16 + m_l)) << 14) + y * 128 + kgrp * 4;
#pragma unroll
    for (int mt = 0; mt < 8; ++mt) {
      f32x4 v = acc[mt][nt];
      float o4[4];
#pragma unroll
      for (int r = 0; r < 4; ++r) {
        float hv = v[r] * scale2[nt] + bias2[nt];
        o4[r] = hv * sigmoidf_(hv);
      }
      *(f32x4*)(out + obase + mt * 16) = (f32x4){o4[0], o4[1], o4[2], o4[3]};
    }
  }
}

// ---------------------------------------------------------------- fused dispatch
// blocks [0,kgN): MFMA kernelgen (short-lived: ~12 GF of MFMA); rest: conv.
// kg blocks finish early and release CU slots to conv -> makespan ~ conv-bound.
__global__ __launch_bounds__(256, 4) void fused_kernel(
    int kgN, const unsigned short* __restrict__ xT, const unsigned short* __restrict__ wT,
    const unsigned short* __restrict__ w1b, const unsigned short* __restrict__ w2b,
    const float* __restrict__ b1f, const float* __restrict__ b2p, float* __restrict__ kern,
    const float* __restrict__ bb, const float* __restrict__ bng, const float* __restrict__ bnb,
    const float* __restrict__ bnm, const float* __restrict__ bnv,
    const unsigned short* __restrict__ zbuf, float* __restrict__ out) {
  __shared__ char smem[33280];  // conv ring 33,280B; kg uses 30,848B
  int blk = (int)blockIdx.x;
  if (blk < kgN) {
    kernelgen_body(blk, xT, w1b, w2b, b1f, b2p, zbuf, kern, smem);
  } else {
    conv_body(blk - kgN, xT, wT, bb, bng, bnb, bnm, bnv, zbuf, out, smem);
  }
}

// ---------------------------------------------------------------- CARAFE + blend (RMW on out)
// XCD-TILE CLUSTERING + pk-fma inner loop (R13 config).
__global__ __launch_bounds__(256) void carafe_blend_kernel(
    const unsigned short* __restrict__ xT, const float* __restrict__ kern,
    const float* __restrict__ gq, float* __restrict__ out) {
  int blk = blockIdx.x;
  int xcd = blk & 7, r = blk >> 3;
  int ocg = r & 15;
  int tile = (r >> 4) * 8 + xcd;  // 0..255
  int b = tile >> 5, rem = tile & 31;
  int by = rem >> 3, bx = rem & 7;
  __shared__ unsigned short xc[720 * 16];  // [36x20 px][16 ch]
  for (int i = threadIdx.x; i < 1440; i += 256) {
    int half = i & 1, p = i >> 1;
    int py = p / 20, pxx = p - py * 20;
    int yy = by * 32 + py - 2, xx = bx * 16 + pxx - 2;
    yy = yy < 0 ? -yy : (yy > 127 ? 254 - yy : yy);
    xx = xx < 0 ? -xx : (xx > 127 ? 254 - xx : xx);
    *(lds_u16x8*)(&xc[p * 16 + half * 8]) =
        *(const u16x8*)(xT + (((size_t)(b << 14)) + yy * 128 + xx) * 256 + ocg * 16 + half * 8);
  }
  __syncthreads();
  int lx = threadIdx.x & 15, y0 = (threadIdx.x >> 4) * 2;
  float gv = gq[b];
  int gy0 = by * 32 + y0, gx = bx * 16 + lx;
  float kv0[25], kv1[25];
  size_t kb = (((size_t)b * 25) << 14) + gy0 * 128 + gx;
#pragma unroll
  for (int n = 0; n < 25; ++n) {
    kv0[n] = kern[kb + ((size_t)n << 14)];
    kv1[n] = kern[kb + ((size_t)n << 14) + 128];
  }
  f32x2 car0[8], car1[8];
#pragma unroll
  for (int c = 0; c < 8; ++c) { car0[c] = (f32x2)0.f; car1[c] = (f32x2)0.f; }
#pragma unroll
  for (int n = 0; n < 25; ++n) {
    int ki = n / 5, kj = n - ki * 5;
    int p0 = (y0 + ki) * 20 + lx + kj;
    f32x2 kvv0 = (f32x2){kv0[n], kv0[n]}, kvv1 = (f32x2){kv1[n], kv1[n]};
    union { u16x8 s8; unsigned int u[4]; } a0, a1, b0, b1;
    a0.s8 = *(lds_u16x8*)(&xc[p0 * 16]);
    a1.s8 = *(lds_u16x8*)(&xc[p0 * 16 + 8]);
    b0.s8 = *(lds_u16x8*)(&xc[(p0 + 20) * 16]);
    b1.s8 = *(lds_u16x8*)(&xc[(p0 + 20) * 16 + 8]);
#pragma unroll
    for (int j = 0; j < 4; ++j) {
      f32x2 f0 = (f32x2){__uint_as_float(a0.u[j] << 16), __uint_as_float(a0.u[j] & 0xffff0000u)};
      f32x2 f1 = (f32x2){__uint_as_float(a1.u[j] << 16), __uint_as_float(a1.u[j] & 0xffff0000u)};
      f32x2 g0 = (f32x2){__uint_as_float(b0.u[j] << 16), __uint_as_float(b0.u[j] & 0xffff0000u)};
      f32x2 g1 = (f32x2){__uint_as_float(b1.u[j] << 16), __uint_as_float(b1.u[j] & 0xffff0000u)};
      car0[j] = pkfma_(f0, kvv0, car0[j]);
      car0[4 + j] = pkfma_(f1, kvv0, car0[4 + j]);
      car1[j] = pkfma_(g0, kvv1, car1[j]);
      car1[4 + j] = pkfma_(g1, kvv1, car1[4 + j]);
    }
  }
#pragma unroll
  for (int j = 0; j < 8; ++j) {
    size_t ob0 = (((size_t)(b * 256 + ocg * 16 + 2 * j)) << 14) + gy0 * 128 + gx;
    size_t ob1 = ob0 + 16384;
    float s00 = out[ob0], s01 = out[ob0 + 128];
    float s10 = out[ob1], s11 = out[ob1 + 128];
    out[ob0] = fmaf(gv, car0[j].x - s00, s00);
    out[ob0 + 128] = fmaf(gv, car1[j].x - s01, s01);
    out[ob1] = fmaf(gv, car0[j].y - s10, s10);
    out[ob1 + 128] = fmaf(gv, car1[j].y - s11, s11);
  }
}

// ---------------------------------------------------------------- launcher
extern "C" void kernel_launch(void* const* d_in, const int* in_sizes, int n_in,
                              void* d_out, int out_size, void* d_ws, size_t ws_size,
                              hipStream_t stream) {
  const float* x      = (const float*)d_in[0];
  const float* ke_w1  = (const float*)d_in[1];
  const float* ke_b1  = (const float*)d_in[2];
  const float* ke_bng = (const float*)d_in[3];
  const float* ke_bnb = (const float*)d_in[4];
  const float* ke_bnm = (const float*)d_in[5];
  const float* ke_bnv = (const float*)d_in[6];
  const float* ke_w2  = (const float*)d_in[7];
  const float* ke_b2  = (const float*)d_in[8];
  const float* bs_w   = (const float*)d_in[9];
  const float* bs_b   = (const float*)d_in[10];
  const float* bs_bng = (const float*)d_in[11];
  const float* bs_bnb = (const float*)d_in[12];
  const float* bs_bnm = (const float*)d_in[13];
  const float* bs_bnv = (const float*)d_in[14];
  const float* g_w    = (const float*)d_in[15];
  const float* g_b    = (const float*)d_in[16];
  float* outp = (float*)d_out;

  char* ws = (char*)d_ws;
  float* kern        = (float*)(ws);                      // 13,107,200 B
  float* partial     = (float*)(ws + 13107200);           // 8,192 B
  float* gout        = (float*)(ws + 13115392);           // bytes 0-31 of 256B slot
  float* zbuff       = (float*)(ws + 13115392 + 128);     // 64B zero pad
  unsigned short* wT = (unsigned short*)(ws + 13115648);  // 1,179,648 B
  unsigned short* xT = (unsigned short*)(ws + 14295296);  // 67,108,864 B -> 81,404,160 total

  // kg MFMA tables (99,456 B): w1b 81,920 + w2b 16,384 + b1f 1,024 + b2p 128.
  // Prefer ws tail (fused launch: conv writes out concurrently -> must not alias
  // d_out). Fallback: dead d_out space + serial launches.
  const size_t USED = 81404160;
  bool bigws = ws_size >= USED + 131072;
  unsigned short *w1b, *w2b;
  float *b1f, *b2p;
  if (bigws) {
    w1b = (unsigned short*)(ws + USED);
    w2b = (unsigned short*)(ws + USED + 81920);
    b1f = (float*)(ws + USED + 98304);
    b2p = (float*)(ws + USED + 99328);
  } else {
    w1b = (unsigned short*)((char*)d_out + 52428800);
    w2b = (unsigned short*)((char*)d_out + 52428800 + 81920);
    b1f = (float*)((char*)d_out + 52428800 + 98304);
    b2p = (float*)((char*)d_out + 52428800 + 99328);
  }

  hipMemsetAsync(partial, 0, 2048 * sizeof(float), stream);  // GAP accumulators
  prep_kernel<<<2497, 256, 0, stream>>>(bs_w, wT, ke_w1, ke_b1, ke_bng, ke_bnb, ke_bnm,
                                        ke_bnv, ke_w2, ke_b2, w1b, w2b, b1f, b2p, zbuff);
  transpose_kernel<<<2048, 256, 0, stream>>>(x, xT, partial);
  gate_kernel<<<8, 256, 0, stream>>>(partial, g_w, g_b, gout);

  if (bigws) {
    fused_kernel<<<2560, 256, 0, stream>>>(512, xT, wT, w1b, w2b, b1f, b2p, kern, bs_b,
                                           bs_bng, bs_bnb, bs_bnm, bs_bnv,
                                           (const unsigned short*)zbuff, outp);
  } else {
    fused_kernel<<<512, 256, 0, stream>>>(512, xT, wT, w1b, w2b, b1f, b2p, kern, bs_b,
                                          bs_bng, bs_bnb, bs_bnm, bs_bnv,
                                          (const unsigned short*)zbuff, outp);
    fused_kernel<<<2048, 256, 0, stream>>>(0, xT, wT, w1b, w2b, b1f, b2p, kern, bs_b,
                                           bs_bng, bs_bnb, bs_bnm, bs_bnv,
                                           (const unsigned short*)zbuff, outp);
  }
  carafe_blend_kernel<<<4096, 256, 0, stream>>>(xT, kern, gout, outp);
}

// Round 15
// 510.308 us; speedup vs baseline: 1.4767x; 1.0208x over previous
//
#include <hip/hip_runtime.h>

#define EPS_ 1e-5f

typedef __attribute__((ext_vector_type(8))) short bf16x8;
typedef __attribute__((ext_vector_type(8))) unsigned short u16x8;
typedef __attribute__((ext_vector_type(4))) unsigned short u16x4;
typedef __attribute__((ext_vector_type(4))) float f32x4;
typedef __attribute__((ext_vector_type(2))) float f32x2;
typedef __attribute__((ext_vector_type(2))) unsigned int u32x2;
typedef __attribute__((address_space(3))) u16x8 lds_u16x8;
typedef __attribute__((address_space(3))) f32x4 lds_f32x4;
typedef __attribute__((address_space(3))) u32x2 lds_u32x2;
typedef __attribute__((address_space(3))) bf16x8 lds_bf16x8;

__device__ __forceinline__ float sigmoidf_(float v) { return 1.f / (1.f + __expf(-v)); }

__device__ __forceinline__ unsigned short f2bf(float f) {
  unsigned int u = __float_as_uint(f);
  u += 0x7fff + ((u >> 16) & 1);  // RNE
  return (unsigned short)(u >> 16);
}

__device__ __forceinline__ float bf2f(unsigned short u) {
  return __uint_as_float((unsigned int)u << 16);
}

// pk-fma: float2 fused multiply-add -> v_pk_fma_f32 on gfx950
__device__ __forceinline__ f32x2 pkfma_(f32x2 a, f32x2 b, f32x2 c) {
#if __has_builtin(__builtin_elementwise_fma)
  return __builtin_elementwise_fma(a, b, c);
#else
  return (f32x2){fmaf(a.x, b.x, c.x), fmaf(a.y, b.y, c.y)};
#endif
}

// async global->LDS, 16B per lane; LDS dest is wave-uniform base (+ lane*16 by HW)
__device__ __forceinline__ void gload16(const void* g, void* l) {
  __builtin_amdgcn_global_load_lds((const __attribute__((address_space(1))) unsigned int*)(g),
                                   (__attribute__((address_space(3))) unsigned int*)(l), 16, 0, 0);
}

// ---------------------------------------------------------------- gate stage 2
__global__ void gate_kernel(const float* __restrict__ partial, const float* __restrict__ gw,
                            const float* __restrict__ gb, float* __restrict__ gout) {
  int b = blockIdx.x, t = threadIdx.x;
  float s = partial[b * 256 + t] * gw[t];
#pragma unroll
  for (int off = 32; off; off >>= 1) s += __shfl_down(s, off, 64);
  __shared__ float red[4];
  if ((t & 63) == 0) red[t >> 6] = s;
  __syncthreads();
  if (t == 0) {
    float tot = (red[0] + red[1]) + (red[2] + red[3]);
    gout[b] = sigmoidf_(tot * (1.f / 16384.f) + gb[0]);
  }
}

// ---------------------------------------------------------------- merged prep
// [0,2304): wtrans. [2304,2464): w1b MFMA-fragment table for grouped conv
// (per group-pair gp: M=16 oc, K=160 (9 taps x 16 ic, zero-padded block-diagonal)).
// [2464,2496): w2b fragment table for the 1x1 (n=25 pad 32, K=256).
// 2496: b1f (BN-folded bias), b2p (b2 padded with -1e30), zbuff.
__global__ void prep_kernel(const float* __restrict__ w, unsigned short* __restrict__ wT,
                            const float* __restrict__ w1, const float* __restrict__ b1,
                            const float* __restrict__ bng, const float* __restrict__ bnb,
                            const float* __restrict__ bnm, const float* __restrict__ bnv,
                            const float* __restrict__ w2, const float* __restrict__ b2,
                            unsigned short* __restrict__ w1b, unsigned short* __restrict__ w2b,
                            float* __restrict__ b1f, float* __restrict__ b2p,
                            float* __restrict__ zb) {
  int blk = blockIdx.x;
  if (blk < 2304) {
    int n = blk * 256 + threadIdx.x;  // 589824
    int c = n & 31, oc = (n >> 5) & 255, t9 = n >> 13;
    int cb = t9 / 9, tap = t9 - cb * 9;
    wT[n] = f2bf(w[(oc * 256 + cb * 32 + c) * 9 + tap]);
  } else if (blk < 2464) {
    int n = (blk - 2304) * 256 + threadIdx.x;  // [0, 40960)
    int j = n & 7, r1 = n >> 3;
    int lane = r1 & 63, r2 = r1 >> 6;  // r2 in [0,80)
    int step = r2 % 5, gp = r2 / 5;
    int oc_l = lane & 15, kg2 = lane >> 4;
    int k = step * 32 + kg2 * 8 + j;
    int tap = k >> 4, icp = k & 15;
    int c = gp * 16 + oc_l;
    bool valid = (tap < 9) && ((icp >> 3) == (oc_l >> 3));
    float s = bng[c] * rsqrtf(bnv[c] + EPS_);
    w1b[n] = f2bf(valid ? w1[c * 72 + (icp & 7) * 9 + tap] * s : 0.f);
  } else if (blk < 2496) {
    int n = (blk - 2464) * 256 + threadIdx.x;  // [0, 8192)
    int j = n & 7, r1 = n >> 3;
    int lane = r1 & 63, r2 = r1 >> 6;  // [0,16)
    int ntile = r2 & 1, rnd = r2 >> 1;
    int nn = ntile * 16 + (lane & 15);
    int c = rnd * 32 + (lane >> 4) * 8 + j;
    w2b[n] = f2bf((nn < 25) ? w2[nn * 256 + c] : 0.f);
  } else {
    int n = threadIdx.x;
    if (n < 16) zb[n] = 0.f;
    if (n < 32) b2p[n] = (n < 25) ? b2[n] : -1e30f;
    if (n < 256) {
      float s = bng[n] * rsqrtf(bnv[n] + EPS_);
      b1f[n] = (b1[n] - bnm[n]) * s + bnb[n];
    }
  }
}

// ---------------------------------------------------------------- x fp32 NCHW -> xT bf16 NHWC
// + fused GAP partial sums (atomicAdd into partial[b*256+ch]; saves a full x re-read).
__global__ __launch_bounds__(256) void transpose_kernel(const float* __restrict__ x,
                                                        unsigned short* __restrict__ xT,
                                                        float* __restrict__ partial) {
  int blk = blockIdx.x;
  int tile = blk & 255, b = blk >> 8;
  int px0 = tile * 64;
  __shared__ unsigned int tr[64 * 130];  // [px][128 ch-pair words + 2 pad]
  for (int i = threadIdx.x; i < 1024; i += 256) {
    int ch2 = i >> 3, pc = i & 7;
    const float* p0 = x + (((size_t)b * 256 + ch2 * 2) << 14) + px0 + pc * 8;
    const float4* a4 = (const float4*)p0;
    const float4* b4 = (const float4*)(p0 + 16384);
    float4 a0 = a4[0], a1 = a4[1], b0 = b4[0], b1 = b4[1];
    float fa[8] = {a0.x, a0.y, a0.z, a0.w, a1.x, a1.y, a1.z, a1.w};
    float fb[8] = {b0.x, b0.y, b0.z, b0.w, b1.x, b1.y, b1.z, b1.w};
    float sa = 0.f, sb = 0.f;
#pragma unroll
    for (int j = 0; j < 8; ++j) {
      sa += fa[j];
      sb += fb[j];
      unsigned int w = (unsigned int)f2bf(fa[j]) | ((unsigned int)f2bf(fb[j]) << 16);
      tr[(pc * 8 + j) * 130 + ch2] = w;
    }
    sa += __shfl_down(sa, 4, 8); sa += __shfl_down(sa, 2, 8); sa += __shfl_down(sa, 1, 8);
    sb += __shfl_down(sb, 4, 8); sb += __shfl_down(sb, 2, 8); sb += __shfl_down(sb, 1, 8);
    if ((threadIdx.x & 7) == 0) {
      atomicAdd(&partial[(b << 8) + ch2 * 2], sa);
      atomicAdd(&partial[(b << 8) + ch2 * 2 + 1], sb);
    }
  }
  __syncthreads();
  for (int i = threadIdx.x; i < 2048; i += 256) {
    int px = i >> 5, kc = i & 31;
    uint4 v = *(uint4*)&tr[px * 130 + kc * 4];
    *(uint4*)(xT + ((((size_t)b << 14)) + px0 + px) * 256 + kc * 8) = v;
  }
}

// ---------------------------------------------------------------- kernelgen via MFMA (R14)
__device__ __forceinline__ void kernelgen_body(
    int kblk, const unsigned short* __restrict__ xT, const unsigned short* __restrict__ w1b,
    const unsigned short* __restrict__ w2b, const float* __restrict__ b1f,
    const float* __restrict__ b2p, const unsigned short* __restrict__ zbuf,
    float* __restrict__ kern, char* smemc) {
  char* hbufc = smemc + 10368;
  int t = kblk & 63, b = kblk >> 6;
  int px0 = (t & 7) * 16, py0 = (t >> 3) * 16;
  int lane = threadIdx.x & 63, wid = threadIdx.x >> 6;
  int nx = lane & 15, kgrp = lane >> 4;
  const char* zc = (const char*)zbuf;

  size_t soff[3];
  bool okk[3];
#pragma unroll
  for (int i = 0; i < 3; ++i) {
    int g = wid * 162 + i * 64 + lane;
    int p = g >> 1, half = g & 1;
    int hy = p / 18, hx = p - hy * 18;
    int gy = py0 + hy - 1, gx = px0 + hx - 1;
    okk[i] = ((unsigned)gy < 128u) && ((unsigned)gx < 128u);
    soff[i] = (size_t)((gy & 127) * 128 + (gx & 127)) * 512 + half * 16;
  }
  const char* imgbase = (const char*)xT + (((size_t)b << 14) * 512);
  int dstb = wid * 2592;

  int aoff[5];
  int base_t = nx * 32 + (kgrp & 1) * 16;
#pragma unroll
  for (int s = 0; s < 5; ++s) {
    int tap = 2 * s + (kgrp >> 1);
    if (tap > 8) tap = 8;
    int dy = tap / 3, dx = tap - dy * 3;
    aoff[s] = dy * 576 + dx * 32 + base_t;
  }

  f32x4 acc2[4][2];
#pragma unroll
  for (int ml = 0; ml < 4; ++ml)
#pragma unroll
    for (int nt = 0; nt < 2; ++nt) acc2[ml][nt] = (f32x4)0.f;

#pragma unroll 1
  for (int gp = 0; gp < 16; ++gp) {
    __syncthreads();  // halo reads of prev round complete
    gload16(okk[0] ? imgbase + soff[0] + gp * 32 : zc, smemc + dstb);
    gload16(okk[1] ? imgbase + soff[1] + gp * 32 : zc, smemc + dstb + 1024);
    if (lane < 34) gload16(okk[2] ? imgbase + soff[2] + gp * 32 : zc, smemc + dstb + 2048);
    asm volatile("s_waitcnt vmcnt(0)" ::: "memory");
    __builtin_amdgcn_s_barrier();
    asm volatile("" ::: "memory");

    bf16x8 wf[5];
    const unsigned short* wp = w1b + ((size_t)(gp * 5) * 64 + lane) * 8;
#pragma unroll
    for (int s = 0; s < 5; ++s) wf[s] = *(const bf16x8*)(wp + s * 512);
    f32x4 bias = *(const f32x4*)(b1f + gp * 16 + kgrp * 4);

#pragma unroll
    for (int ml = 0; ml < 4; ++ml) {
      int m = wid * 4 + ml;
      f32x4 cf = (f32x4)0.f;
#pragma unroll
      for (int s = 0; s < 5; ++s) {
        bf16x8 xf = *(lds_bf16x8*)(smemc + m * 576 + aoff[s]);
        cf = __builtin_amdgcn_mfma_f32_16x16x32_bf16(wf[s], xf, cf, 0, 0, 0);
      }
      unsigned short us[4];
#pragma unroll
      for (int r = 0; r < 4; ++r) {
        float hv = cf[r] + bias[r];
        us[r] = f2bf(hv * sigmoidf_(hv));
      }
      unsigned int lo = (unsigned int)us[0] | ((unsigned int)us[1] << 16);
      unsigned int hi = (unsigned int)us[2] | ((unsigned int)us[3] << 16);
      *(lds_u32x2*)(hbufc + (m * 16 + nx) * 80 + (gp & 1) * 32 + kgrp * 8) = (u32x2){lo, hi};
    }

    if (gp & 1) {  // 32-ch window complete -> 1x1 MFMA chunk
      int rnd = gp >> 1;
      const unsigned short* w2p = w2b + ((size_t)(rnd * 2) * 64 + lane) * 8;
      bf16x8 w2f0 = *(const bf16x8*)(w2p);
      bf16x8 w2f1 = *(const bf16x8*)(w2p + 512);
#pragma unroll
      for (int ml = 0; ml < 4; ++ml) {
        int m = wid * 4 + ml;
        bf16x8 hf = *(lds_bf16x8*)(hbufc + (m * 16 + nx) * 80 + kgrp * 16);
        acc2[ml][0] = __builtin_amdgcn_mfma_f32_16x16x32_bf16(w2f0, hf, acc2[ml][0], 0, 0, 0);
        acc2[ml][1] = __builtin_amdgcn_mfma_f32_16x16x32_bf16(w2f1, hf, acc2[ml][1], 0, 0, 0);
      }
    }
  }

  f32x4 blo = *(const f32x4*)(b2p + kgrp * 4);
  f32x4 bhi = *(const f32x4*)(b2p + 16 + kgrp * 4);
#pragma unroll
  for (int ml = 0; ml < 4; ++ml) {
    int m = wid * 4 + ml;
    float v[8];
#pragma unroll
    for (int r = 0; r < 4; ++r) {
      v[r] = acc2[ml][0][r] + blo[r];
      v[4 + r] = acc2[ml][1][r] + bhi[r];
    }
    float mx = v[0];
#pragma unroll
    for (int i = 1; i < 8; ++i) mx = fmaxf(mx, v[i]);
    mx = fmaxf(mx, __shfl_xor(mx, 16, 64));
    mx = fmaxf(mx, __shfl_xor(mx, 32, 64));
    float sum = 0.f;
#pragma unroll
    for (int i = 0; i < 8; ++i) { v[i] = __expf(v[i] - mx); sum += v[i]; }
    sum += __shfl_xor(sum, 16, 64);
    sum += __shfl_xor(sum, 32, 64);
    float inv = 1.f / sum;
    size_t base = (((size_t)b * 25) << 14) + (size_t)(py0 + m) * 128 + px0 + nx;
#pragma unroll
    for (int nt = 0; nt < 2; ++nt)
#pragma unroll
      for (int r = 0; r < 4; ++r) {
        int n = nt * 16 + kgrp * 4 + r;
        if (n < 25) kern[base + ((size_t)n << 14)] = v[nt * 4 + r] * inv;
      }
  }
}

// conv body (R10 config) + statb epilogue: when statb != null the static branch is
// written as bf16 to statb (write-only out path for carafe); else fp32 to out (RMW path).
__device__ __forceinline__ void conv_body(int cblk, const unsigned short* __restrict__ xT,
                                          const unsigned short* __restrict__ wT,
                                          const float* __restrict__ bb,
                                          const float* __restrict__ bng,
                                          const float* __restrict__ bnb,
                                          const float* __restrict__ bnm,
                                          const float* __restrict__ bnv,
                                          const unsigned short* __restrict__ zbuf,
                                          unsigned short* __restrict__ statb,
                                          float* __restrict__ out, char* smemc) {
  int nb = ((cblk & 7) << 8) | (cblk >> 3);  // XCD swizzle (2048 % 8 == 0)
  int ocb = nb & 1, y = (nb >> 1) & 127, b = nb >> 8;
  int lane = threadIdx.x & 63, wid = threadIdx.x >> 6;
  int m_l = lane & 15, kgrp = lane >> 4;

  unsigned short* xs = (unsigned short*)smemc;  // ring: 4 x 8320B row slots
  const char* zc = (const char*)zbuf;

  int g0 = wid * 130 + lane, g1 = g0 + 64, g2 = wid * 130 + 128 + lane;  // g2: lane<2
  int px0_ = g0 >> 2, k0_ = g0 & 3, s0_ = k0_ ^ ((px0_ >> 1) & 3), gx0 = px0_ - 1;
  int px1_ = g1 >> 2, k1_ = g1 & 3, s1_ = k1_ ^ ((px1_ >> 1) & 3), gx1 = px1_ - 1;
  int px2_ = g2 >> 2, k2_ = g2 & 3, s2_ = k2_ ^ ((px2_ >> 1) & 3), gx2 = px2_ - 1;
  bool ok0 = (unsigned)gx0 < 128u, ok1 = (unsigned)gx1 < 128u, ok2 = (unsigned)gx2 < 128u;
  int off0 = gx0 * 512 + s0_ * 16, off1 = gx1 * 512 + s1_ * 16, off2 = gx2 * 512 + s2_ * 16;
  int d0 = (wid * 130) * 16, d1 = d0 + 1024, d2 = d0 + 2048;

#define STAGE_ROW(slotB_, cbn_, khn_)                                                       \
  do {                                                                                      \
    int gy_ = y + (khn_)-1;                                                                 \
    bool gyok_ = ((unsigned)gy_ < 128u);                                                    \
    const char* rb_ =                                                                       \
        (const char*)xT + (((size_t)b << 14) + (size_t)(gy_ & 127) * 128) * 512 + (cbn_)*64;\
    gload16((gyok_ && ok0) ? rb_ + off0 : zc, smemc + (slotB_) + d0);                       \
    gload16((gyok_ && ok1) ? rb_ + off1 : zc, smemc + (slotB_) + d1);                       \
    if (lane < 2) gload16((gyok_ && ok2) ? rb_ + off2 : zc, smemc + (slotB_) + d2);         \
  } while (0)

  f32x4 acc[8][2];
#pragma unroll
  for (int mt = 0; mt < 8; ++mt)
#pragma unroll
    for (int nt = 0; nt < 2; ++nt) acc[mt][nt] = (f32x4)0.f;

  STAGE_ROW(0, 0, 0);
  STAGE_ROW(8320, 0, 1);
  STAGE_ROW(16640, 0, 2);
  STAGE_ROW(24960, 1, 0);

  int oc0 = ocb * 128 + wid * 32;
  const unsigned short* wTb = wT + ((size_t)(oc0 + m_l) * 32 + kgrp * 8);
  int khn = 1, cbn = 1;

#pragma unroll 1
  for (int P = 0; P < 12; ++P) {
    if (P < 11) {
      asm volatile("s_waitcnt vmcnt(6)" ::: "memory");
    } else {
      asm volatile("s_waitcnt vmcnt(0)" ::: "memory");
    }
    __builtin_amdgcn_s_barrier();
    asm volatile("" ::: "memory");
#pragma unroll
    for (int half = 0; half < 2; ++half) {
      int R = 2 * P + half;
      const unsigned short* xb = xs + (R & 3) * 4160;
#pragma unroll
      for (int kw = 0; kw < 3; ++kw) {
        bf16x8 bfrag[2];
        const unsigned short* wb = wTb + (size_t)(R * 3 + kw) * 8192;
#pragma unroll
        for (int nt = 0; nt < 2; ++nt) bfrag[nt] = *(const bf16x8*)(wb + nt * 512);
#pragma unroll
        for (int mt = 0; mt < 8; ++mt) {
          int apx = mt * 16 + m_l + kw;
          int kk = kgrp ^ ((apx >> 1) & 3);
          bf16x8 af =
              *(__attribute__((address_space(3))) bf16x8*)(&xb[apx * 32 + kk * 8]);
#pragma unroll
          for (int nt = 0; nt < 2; ++nt)
            acc[mt][nt] =
                __builtin_amdgcn_mfma_f32_16x16x32_bf16(af, bfrag[nt], acc[mt][nt], 0, 0, 0);
        }
      }
    }
    __builtin_amdgcn_s_barrier();
    asm volatile("" ::: "memory");
    if (P < 10) {
      STAGE_ROW((size_t)((2 * P + 4) & 3) * 8320, cbn, khn);
      ++khn;
      if (khn == 3) { khn = 0; ++cbn; }
      STAGE_ROW((size_t)((2 * P + 5) & 3) * 8320, cbn, khn);
      ++khn;
      if (khn == 3) { khn = 0; ++cbn; }
    }
  }
#undef STAGE_ROW

  float scale2[2], bias2[2];
#pragma unroll
  for (int nt = 0; nt < 2; ++nt) {
    int oc = oc0 + nt * 16 + m_l;
    float s = bng[oc] * rsqrtf(bnv[oc] + EPS_);
    scale2[nt] = s;
    bias2[nt] = bnb[oc] + (bb[oc] - bnm[oc]) * s;
  }
  if (statb) {
#pragma unroll
    for (int nt = 0; nt < 2; ++nt) {
      size_t obase = (((size_t)(b * 256 + oc0 + nt * 16 + m_l)) << 14) + y * 128 + kgrp * 4;
#pragma unroll
      for (int mt = 0; mt < 8; ++mt) {
        f32x4 v = acc[mt][nt];
        u16x4 o;
#pragma unroll
        for (int r = 0; r < 4; ++r) {
          float hv = v[r] * scale2[nt] + bias2[nt];
          o[r] = f2bf(hv * sigmoidf_(hv));
        }
        *(u16x4*)(statb + obase + mt * 16) = o;
      }
    }
  } else {
#pragma unroll
    for (int nt = 0; nt < 2; ++nt) {
      size_t obase = (((size_t)(b * 256 + oc0 + nt * 16 + m_l)) << 14) + y * 128 + kgrp * 4;
#pragma unroll
      for (int mt = 0; mt < 8; ++mt) {
        f32x4 v = acc[mt][nt];
        float o4[4];
#pragma unroll
        for (int r = 0; r < 4; ++r) {
          float hv = v[r] * scale2[nt] + bias2[nt];
          o4[r] = hv * sigmoidf_(hv);
        }
        *(f32x4*)(out + obase + mt * 16) = (f32x4){o4[0], o4[1], o4[2], o4[3]};
      }
    }
  }
}

// ---------------------------------------------------------------- fused dispatch
__global__ __launch_bounds__(256, 4) void fused_kernel(
    int kgN, const unsigned short* __restrict__ xT, const unsigned short* __restrict__ wT,
    const unsigned short* __restrict__ w1b, const unsigned short* __restrict__ w2b,
    const float* __restrict__ b1f, const float* __restrict__ b2p, float* __restrict__ kern,
    const float* __restrict__ bb, const float* __restrict__ bng, const float* __restrict__ bnb,
    const float* __restrict__ bnm, const float* __restrict__ bnv,
    const unsigned short* __restrict__ zbuf, unsigned short* __restrict__ statb,
    float* __restrict__ out) {
  __shared__ char smem[33280];  // conv ring 33,280B; kg uses 30,848B
  int blk = (int)blockIdx.x;
  if (blk < kgN) {
    kernelgen_body(blk, xT, w1b, w2b, b1f, b2p, zbuf, kern, smem);
  } else {
    conv_body(blk - kgN, xT, wT, bb, bng, bnb, bnm, bnv, zbuf, statb, out, smem);
  }
}

// ---------------------------------------------------------------- CARAFE + blend
// XCD-TILE CLUSTERING + pk-fma inner loop. Halo staged via global_load_lds (layout
// is lane-linear: granule g -> byte g*16; per-lane SOURCE carries reflect indexing).
// kern prefetched before staging (latency hides under DMA). statb path: read bf16
// static, write out once (no RMW); fallback: fp32 RMW on out.
__global__ __launch_bounds__(256) void carafe_blend_kernel(
    const unsigned short* __restrict__ xT, const float* __restrict__ kern,
    const float* __restrict__ gq, const unsigned short* __restrict__ statb,
    float* __restrict__ out) {
  int blk = blockIdx.x;
  int xcd = blk & 7, r = blk >> 3;
  int ocg = r & 15;
  int tile = (r >> 4) * 8 + xcd;  // 0..255
  int b = tile >> 5, rem = tile & 31;
  int by = rem >> 3, bx = rem & 7;
  __shared__ unsigned short xc[720 * 16];  // [36x20 px][16 ch]
  int lane = threadIdx.x & 63, wid = threadIdx.x >> 6;
  int lx = threadIdx.x & 15, y0 = (threadIdx.x >> 4) * 2;
  float gv = gq[b];
  int gy0 = by * 32 + y0, gx = bx * 16 + lx;

  // kern prefetch (issued before staging DMA)
  float kv0[25], kv1[25];
  size_t kb = (((size_t)b * 25) << 14) + gy0 * 128 + gx;
#pragma unroll
  for (int n = 0; n < 25; ++n) {
    kv0[n] = kern[kb + ((size_t)n << 14)];
    kv1[n] = kern[kb + ((size_t)n << 14) + 128];
  }

  // halo staging: 1440 granules of 16B, wave w covers [w*360, w*360+360)
  int dstb = wid * 5760;
#pragma unroll
  for (int i = 0; i < 6; ++i) {
    int g = wid * 360 + i * 64 + lane;
    if (i < 5 || lane < 40) {
      int p = g >> 1, half = g & 1;
      int py = p / 20, pxx = p - py * 20;
      int yy = by * 32 + py - 2, xx = bx * 16 + pxx - 2;
      yy = yy < 0 ? -yy : (yy > 127 ? 254 - yy : yy);
      xx = xx < 0 ? -xx : (xx > 127 ? 254 - xx : xx);
      gload16((const char*)xT + ((size_t)((b << 14) + yy * 128 + xx) * 512) + ocg * 32 +
                  half * 16,
              (char*)xc + dstb + i * 1024);
    }
  }
  asm volatile("s_waitcnt vmcnt(0)" ::: "memory");
  __syncthreads();

  f32x2 car0[8], car1[8];
#pragma unroll
  for (int c = 0; c < 8; ++c) { car0[c] = (f32x2)0.f; car1[c] = (f32x2)0.f; }
#pragma unroll
  for (int n = 0; n < 25; ++n) {
    int ki = n / 5, kj = n - ki * 5;
    int p0 = (y0 + ki) * 20 + lx + kj;
    f32x2 kvv0 = (f32x2){kv0[n], kv0[n]}, kvv1 = (f32x2){kv1[n], kv1[n]};
    union { u16x8 s8; unsigned int u[4]; } a0, a1, b0, b1;
    a0.s8 = *(lds_u16x8*)(&xc[p0 * 16]);
    a1.s8 = *(lds_u16x8*)(&xc[p0 * 16 + 8]);
    b0.s8 = *(lds_u16x8*)(&xc[(p0 + 20) * 16]);
    b1.s8 = *(lds_u16x8*)(&xc[(p0 + 20) * 16 + 8]);
#pragma unroll
    for (int j = 0; j < 4; ++j) {
      f32x2 f0 = (f32x2){__uint_as_float(a0.u[j] << 16), __uint_as_float(a0.u[j] & 0xffff0000u)};
      f32x2 f1 = (f32x2){__uint_as_float(a1.u[j] << 16), __uint_as_float(a1.u[j] & 0xffff0000u)};
      f32x2 g0 = (f32x2){__uint_as_float(b0.u[j] << 16), __uint_as_float(b0.u[j] & 0xffff0000u)};
      f32x2 g1 = (f32x2){__uint_as_float(b1.u[j] << 16), __uint_as_float(b1.u[j] & 0xffff0000u)};
      car0[j] = pkfma_(f0, kvv0, car0[j]);
      car0[4 + j] = pkfma_(f1, kvv0, car0[4 + j]);
      car1[j] = pkfma_(g0, kvv1, car1[j]);
      car1[4 + j] = pkfma_(g1, kvv1, car1[4 + j]);
    }
  }
  if (statb) {
#pragma unroll
    for (int j = 0; j < 8; ++j) {
      size_t ob0 = (((size_t)(b * 256 + ocg * 16 + 2 * j)) << 14) + gy0 * 128 + gx;
      size_t ob1 = ob0 + 16384;
      float s00 = bf2f(statb[ob0]), s01 = bf2f(statb[ob0 + 128]);
      float s10 = bf2f(statb[ob1]), s11 = bf2f(statb[ob1 + 128]);
      out[ob0] = fmaf(gv, car0[j].x - s00, s00);
      out[ob0 + 128] = fmaf(gv, car1[j].x - s01, s01);
      out[ob1] = fmaf(gv, car0[j].y - s10, s10);
      out[ob1 + 128] = fmaf(gv, car1[j].y - s11, s11);
    }
  } else {
#pragma unroll
    for (int j = 0; j < 8; ++j) {
      size_t ob0 = (((size_t)(b * 256 + ocg * 16 + 2 * j)) << 14) + gy0 * 128 + gx;
      size_t ob1 = ob0 + 16384;
      float s00 = out[ob0], s01 = out[ob0 + 128];
      float s10 = out[ob1], s11 = out[ob1 + 128];
      out[ob0] = fmaf(gv, car0[j].x - s00, s00);
      out[ob0 + 128] = fmaf(gv, car1[j].x - s01, s01);
      out[ob1] = fmaf(gv, car0[j].y - s10, s10);
      out[ob1 + 128] = fmaf(gv, car1[j].y - s11, s11);
    }
  }
}

// ---------------------------------------------------------------- launcher
extern "C" void kernel_launch(void* const* d_in, const int* in_sizes, int n_in,
                              void* d_out, int out_size, void* d_ws, size_t ws_size,
                              hipStream_t stream) {
  const float* x      = (const float*)d_in[0];
  const float* ke_w1  = (const float*)d_in[1];
  const float* ke_b1  = (const float*)d_in[2];
  const float* ke_bng = (const float*)d_in[3];
  const float* ke_bnb = (const float*)d_in[4];
  const float* ke_bnm = (const float*)d_in[5];
  const float* ke_bnv = (const float*)d_in[6];
  const float* ke_w2  = (const float*)d_in[7];
  const float* ke_b2  = (const float*)d_in[8];
  const float* bs_w   = (const float*)d_in[9];
  const float* bs_b   = (const float*)d_in[10];
  const float* bs_bng = (const float*)d_in[11];
  const float* bs_bnb = (const float*)d_in[12];
  const float* bs_bnm = (const float*)d_in[13];
  const float* bs_bnv = (const float*)d_in[14];
  const float* g_w    = (const float*)d_in[15];
  const float* g_b    = (const float*)d_in[16];
  float* outp = (float*)d_out;

  char* ws = (char*)d_ws;
  float* kern        = (float*)(ws);                      // 13,107,200 B
  float* partial     = (float*)(ws + 13107200);           // 8,192 B
  float* gout        = (float*)(ws + 13115392);           // bytes 0-31 of 256B slot
  float* zbuff       = (float*)(ws + 13115392 + 128);     // 64B zero pad
  unsigned short* wT = (unsigned short*)(ws + 13115648);  // 1,179,648 B
  unsigned short* xT = (unsigned short*)(ws + 14295296);  // 67,108,864 B -> 81,404,160 total

  // kg MFMA tables (99,456 B in a 131,072 B slot) + optional bf16 static buffer
  // (67,108,864 B). statb enables write-only out in carafe (no RMW read).
  const size_t USED = 81404160;
  const size_t TBL = 131072;
  bool bigws = ws_size >= USED + TBL;
  bool bigws2 = ws_size >= USED + TBL + 67108864;
  unsigned short *w1b, *w2b;
  float *b1f, *b2p;
  if (bigws) {
    w1b = (unsigned short*)(ws + USED);
    w2b = (unsigned short*)(ws + USED + 81920);
    b1f = (float*)(ws + USED + 98304);
    b2p = (float*)(ws + USED + 99328);
  } else {
    w1b = (unsigned short*)((char*)d_out + 52428800);
    w2b = (unsigned short*)((char*)d_out + 52428800 + 81920);
    b1f = (float*)((char*)d_out + 52428800 + 98304);
    b2p = (float*)((char*)d_out + 52428800 + 99328);
  }
  unsigned short* statb = bigws2 ? (unsigned short*)(ws + USED + TBL) : nullptr;

  hipMemsetAsync(partial, 0, 2048 * sizeof(float), stream);  // GAP accumulators
  prep_kernel<<<2497, 256, 0, stream>>>(bs_w, wT, ke_w1, ke_b1, ke_bng, ke_bnb, ke_bnm,
                                        ke_bnv, ke_w2, ke_b2, w1b, w2b, b1f, b2p, zbuff);
  transpose_kernel<<<2048, 256, 0, stream>>>(x, xT, partial);
  gate_kernel<<<8, 256, 0, stream>>>(partial, g_w, g_b, gout);

  if (bigws) {
    fused_kernel<<<2560, 256, 0, stream>>>(512, xT, wT, w1b, w2b, b1f, b2p, kern, bs_b,
                                           bs_bng, bs_bnb, bs_bnm, bs_bnv,
                                           (const unsigned short*)zbuff, statb, outp);
  } else {
    fused_kernel<<<512, 256, 0, stream>>>(512, xT, wT, w1b, w2b, b1f, b2p, kern, bs_b,
                                          bs_bng, bs_bnb, bs_bnm, bs_bnv,
                                          (const unsigned short*)zbuff, statb, outp);
    fused_kernel<<<2048, 256, 0, stream>>>(0, xT, wT, w1b, w2b, b1f, b2p, kern, bs_b,
                                           bs_bng, bs_bnb, bs_bnm, bs_bnv,
                                           (const unsigned short*)zbuff, statb, outp);
  }
  carafe_blend_kernel<<<4096, 256, 0, stream>>>(xT, kern, gout, statb, outp);
}

// Round 16
// 476.235 us; speedup vs baseline: 1.5823x; 1.0715x over previous
//
#include <hip/hip_runtime.h>

#define EPS_ 1e-5f

typedef __attribute__((ext_vector_type(8))) short bf16x8;
typedef __attribute__((ext_vector_type(8))) unsigned short u16x8;
typedef __attribute__((ext_vector_type(4))) unsigned short u16x4;
typedef __attribute__((ext_vector_type(4))) float f32x4;
typedef __attribute__((ext_vector_type(2))) float f32x2;
typedef __attribute__((ext_vector_type(2))) unsigned int u32x2;
typedef __attribute__((address_space(3))) u16x8 lds_u16x8;
typedef __attribute__((address_space(3))) f32x4 lds_f32x4;
typedef __attribute__((address_space(3))) u32x2 lds_u32x2;
typedef __attribute__((address_space(3))) bf16x8 lds_bf16x8;

__device__ __forceinline__ float sigmoidf_(float v) { return 1.f / (1.f + __expf(-v)); }

__device__ __forceinline__ unsigned short f2bf(float f) {
  unsigned int u = __float_as_uint(f);
  u += 0x7fff + ((u >> 16) & 1);  // RNE
  return (unsigned short)(u >> 16);
}

__device__ __forceinline__ float bf2f(unsigned short u) {
  return __uint_as_float((unsigned int)u << 16);
}

// pk-fma: float2 fused multiply-add -> v_pk_fma_f32 on gfx950
__device__ __forceinline__ f32x2 pkfma_(f32x2 a, f32x2 b, f32x2 c) {
#if __has_builtin(__builtin_elementwise_fma)
  return __builtin_elementwise_fma(a, b, c);
#else
  return (f32x2){fmaf(a.x, b.x, c.x), fmaf(a.y, b.y, c.y)};
#endif
}

// async global->LDS, 16B per lane; LDS dest is wave-uniform base (+ lane*16 by HW)
__device__ __forceinline__ void gload16(const void* g, void* l) {
  __builtin_amdgcn_global_load_lds((const __attribute__((address_space(1))) unsigned int*)(g),
                                   (__attribute__((address_space(3))) unsigned int*)(l), 16, 0, 0);
}

// ---------------------------------------------------------------- dispatch A: transpose + prep
// blocks [0,2048): x fp32 NCHW -> xT bf16 NHWC + fused GAP partials (BW-bound).
// blocks [2048,4545): weight prep (latency-bound; overlaps transpose on the CU).
__global__ __launch_bounds__(256) void prep_transpose_kernel(
    const float* __restrict__ x, unsigned short* __restrict__ xT, float* __restrict__ partial,
    const float* __restrict__ w, unsigned short* __restrict__ wT,
    const float* __restrict__ w1, const float* __restrict__ b1, const float* __restrict__ bng,
    const float* __restrict__ bnb, const float* __restrict__ bnm, const float* __restrict__ bnv,
    const float* __restrict__ w2, const float* __restrict__ b2,
    unsigned short* __restrict__ w1b, unsigned short* __restrict__ w2b,
    float* __restrict__ b1f, float* __restrict__ b2p, float* __restrict__ zb) {
  __shared__ unsigned int tr[64 * 130];  // transpose: [px][128 ch-pair words + 2 pad]
  int ablk = blockIdx.x;
  if (ablk < 2048) {
    int tile = ablk & 255, b = ablk >> 8;
    int px0 = tile * 64;
    for (int i = threadIdx.x; i < 1024; i += 256) {
      int ch2 = i >> 3, pc = i & 7;
      const float* p0 = x + (((size_t)b * 256 + ch2 * 2) << 14) + px0 + pc * 8;
      const float4* a4 = (const float4*)p0;
      const float4* b4 = (const float4*)(p0 + 16384);
      float4 a0 = a4[0], a1 = a4[1], b0 = b4[0], b1v = b4[1];
      float fa[8] = {a0.x, a0.y, a0.z, a0.w, a1.x, a1.y, a1.z, a1.w};
      float fb[8] = {b0.x, b0.y, b0.z, b0.w, b1v.x, b1v.y, b1v.z, b1v.w};
      float sa = 0.f, sb = 0.f;
#pragma unroll
      for (int j = 0; j < 8; ++j) {
        sa += fa[j];
        sb += fb[j];
        unsigned int wv = (unsigned int)f2bf(fa[j]) | ((unsigned int)f2bf(fb[j]) << 16);
        tr[(pc * 8 + j) * 130 + ch2] = wv;
      }
      sa += __shfl_down(sa, 4, 8); sa += __shfl_down(sa, 2, 8); sa += __shfl_down(sa, 1, 8);
      sb += __shfl_down(sb, 4, 8); sb += __shfl_down(sb, 2, 8); sb += __shfl_down(sb, 1, 8);
      if ((threadIdx.x & 7) == 0) {
        atomicAdd(&partial[(b << 8) + ch2 * 2], sa);
        atomicAdd(&partial[(b << 8) + ch2 * 2 + 1], sb);
      }
    }
    __syncthreads();
    for (int i = threadIdx.x; i < 2048; i += 256) {
      int px = i >> 5, kc = i & 31;
      uint4 v = *(uint4*)&tr[px * 130 + kc * 4];
      *(uint4*)(xT + ((((size_t)b << 14)) + px0 + px) * 256 + kc * 8) = v;
    }
    return;
  }
  int blk = ablk - 2048;  // prep: 2497 blocks
  if (blk < 2304) {
    int n = blk * 256 + threadIdx.x;  // 589824
    int c = n & 31, oc = (n >> 5) & 255, t9 = n >> 13;
    int cb = t9 / 9, tap = t9 - cb * 9;
    wT[n] = f2bf(w[(oc * 256 + cb * 32 + c) * 9 + tap]);
  } else if (blk < 2464) {
    int n = (blk - 2304) * 256 + threadIdx.x;  // [0, 40960)
    int j = n & 7, r1 = n >> 3;
    int lane = r1 & 63, r2 = r1 >> 6;  // r2 in [0,80)
    int step = r2 % 5, gp = r2 / 5;
    int oc_l = lane & 15, kg2 = lane >> 4;
    int k = step * 32 + kg2 * 8 + j;
    int tap = k >> 4, icp = k & 15;
    int c = gp * 16 + oc_l;
    bool valid = (tap < 9) && ((icp >> 3) == (oc_l >> 3));
    float s = bng[c] * rsqrtf(bnv[c] + EPS_);
    w1b[n] = f2bf(valid ? w1[c * 72 + (icp & 7) * 9 + tap] * s : 0.f);
  } else if (blk < 2496) {
    int n = (blk - 2464) * 256 + threadIdx.x;  // [0, 8192)
    int j = n & 7, r1 = n >> 3;
    int lane = r1 & 63, r2 = r1 >> 6;  // [0,16)
    int ntile = r2 & 1, rnd = r2 >> 1;
    int nn = ntile * 16 + (lane & 15);
    int c = rnd * 32 + (lane >> 4) * 8 + j;
    w2b[n] = f2bf((nn < 25) ? w2[nn * 256 + c] : 0.f);
  } else {
    int n = threadIdx.x;
    if (n < 16) zb[n] = 0.f;
    if (n < 32) b2p[n] = (n < 25) ? b2[n] : -1e30f;
    if (n < 256) {
      float s = bng[n] * rsqrtf(bnv[n] + EPS_);
      b1f[n] = (b1[n] - bnm[n]) * s + bnb[n];
    }
  }
}

// ---------------------------------------------------------------- kernelgen via MFMA (R14)
__device__ __forceinline__ void kernelgen_body(
    int kblk, const unsigned short* __restrict__ xT, const unsigned short* __restrict__ w1b,
    const unsigned short* __restrict__ w2b, const float* __restrict__ b1f,
    const float* __restrict__ b2p, const unsigned short* __restrict__ zbuf,
    float* __restrict__ kern, char* smemc) {
  char* hbufc = smemc + 10368;
  int t = kblk & 63, b = kblk >> 6;
  int px0 = (t & 7) * 16, py0 = (t >> 3) * 16;
  int lane = threadIdx.x & 63, wid = threadIdx.x >> 6;
  int nx = lane & 15, kgrp = lane >> 4;
  const char* zc = (const char*)zbuf;

  size_t soff[3];
  bool okk[3];
#pragma unroll
  for (int i = 0; i < 3; ++i) {
    int g = wid * 162 + i * 64 + lane;
    int p = g >> 1, half = g & 1;
    int hy = p / 18, hx = p - hy * 18;
    int gy = py0 + hy - 1, gx = px0 + hx - 1;
    okk[i] = ((unsigned)gy < 128u) && ((unsigned)gx < 128u);
    soff[i] = (size_t)((gy & 127) * 128 + (gx & 127)) * 512 + half * 16;
  }
  const char* imgbase = (const char*)xT + (((size_t)b << 14) * 512);
  int dstb = wid * 2592;

  int aoff[5];
  int base_t = nx * 32 + (kgrp & 1) * 16;
#pragma unroll
  for (int s = 0; s < 5; ++s) {
    int tap = 2 * s + (kgrp >> 1);
    if (tap > 8) tap = 8;
    int dy = tap / 3, dx = tap - dy * 3;
    aoff[s] = dy * 576 + dx * 32 + base_t;
  }

  f32x4 acc2[4][2];
#pragma unroll
  for (int ml = 0; ml < 4; ++ml)
#pragma unroll
    for (int nt = 0; nt < 2; ++nt) acc2[ml][nt] = (f32x4)0.f;

#pragma unroll 1
  for (int gp = 0; gp < 16; ++gp) {
    __syncthreads();  // halo reads of prev round complete
    gload16(okk[0] ? imgbase + soff[0] + gp * 32 : zc, smemc + dstb);
    gload16(okk[1] ? imgbase + soff[1] + gp * 32 : zc, smemc + dstb + 1024);
    if (lane < 34) gload16(okk[2] ? imgbase + soff[2] + gp * 32 : zc, smemc + dstb + 2048);
    asm volatile("s_waitcnt vmcnt(0)" ::: "memory");
    __builtin_amdgcn_s_barrier();
    asm volatile("" ::: "memory");

    bf16x8 wf[5];
    const unsigned short* wp = w1b + ((size_t)(gp * 5) * 64 + lane) * 8;
#pragma unroll
    for (int s = 0; s < 5; ++s) wf[s] = *(const bf16x8*)(wp + s * 512);
    f32x4 bias = *(const f32x4*)(b1f + gp * 16 + kgrp * 4);

#pragma unroll
    for (int ml = 0; ml < 4; ++ml) {
      int m = wid * 4 + ml;
      f32x4 cf = (f32x4)0.f;
#pragma unroll
      for (int s = 0; s < 5; ++s) {
        bf16x8 xf = *(lds_bf16x8*)(smemc + m * 576 + aoff[s]);
        cf = __builtin_amdgcn_mfma_f32_16x16x32_bf16(wf[s], xf, cf, 0, 0, 0);
      }
      unsigned short us[4];
#pragma unroll
      for (int r = 0; r < 4; ++r) {
        float hv = cf[r] + bias[r];
        us[r] = f2bf(hv * sigmoidf_(hv));
      }
      unsigned int lo = (unsigned int)us[0] | ((unsigned int)us[1] << 16);
      unsigned int hi = (unsigned int)us[2] | ((unsigned int)us[3] << 16);
      *(lds_u32x2*)(hbufc + (m * 16 + nx) * 80 + (gp & 1) * 32 + kgrp * 8) = (u32x2){lo, hi};
    }

    if (gp & 1) {  // 32-ch window complete -> 1x1 MFMA chunk
      int rnd = gp >> 1;
      const unsigned short* w2p = w2b + ((size_t)(rnd * 2) * 64 + lane) * 8;
      bf16x8 w2f0 = *(const bf16x8*)(w2p);
      bf16x8 w2f1 = *(const bf16x8*)(w2p + 512);
#pragma unroll
      for (int ml = 0; ml < 4; ++ml) {
        int m = wid * 4 + ml;
        bf16x8 hf = *(lds_bf16x8*)(hbufc + (m * 16 + nx) * 80 + kgrp * 16);
        acc2[ml][0] = __builtin_amdgcn_mfma_f32_16x16x32_bf16(w2f0, hf, acc2[ml][0], 0, 0, 0);
        acc2[ml][1] = __builtin_amdgcn_mfma_f32_16x16x32_bf16(w2f1, hf, acc2[ml][1], 0, 0, 0);
      }
    }
  }

  f32x4 blo = *(const f32x4*)(b2p + kgrp * 4);
  f32x4 bhi = *(const f32x4*)(b2p + 16 + kgrp * 4);
#pragma unroll
  for (int ml = 0; ml < 4; ++ml) {
    int m = wid * 4 + ml;
    float v[8];
#pragma unroll
    for (int r = 0; r < 4; ++r) {
      v[r] = acc2[ml][0][r] + blo[r];
      v[4 + r] = acc2[ml][1][r] + bhi[r];
    }
    float mx = v[0];
#pragma unroll
    for (int i = 1; i < 8; ++i) mx = fmaxf(mx, v[i]);
    mx = fmaxf(mx, __shfl_xor(mx, 16, 64));
    mx = fmaxf(mx, __shfl_xor(mx, 32, 64));
    float sum = 0.f;
#pragma unroll
    for (int i = 0; i < 8; ++i) { v[i] = __expf(v[i] - mx); sum += v[i]; }
    sum += __shfl_xor(sum, 16, 64);
    sum += __shfl_xor(sum, 32, 64);
    float inv = 1.f / sum;
    size_t base = (((size_t)b * 25) << 14) + (size_t)(py0 + m) * 128 + px0 + nx;
#pragma unroll
    for (int nt = 0; nt < 2; ++nt)
#pragma unroll
      for (int r = 0; r < 4; ++r) {
        int n = nt * 16 + kgrp * 4 + r;
        if (n < 25) kern[base + ((size_t)n << 14)] = v[nt * 4 + r] * inv;
      }
  }
}

// conv body (R10 config) + statb epilogue (bf16 static when statb != null).
__device__ __forceinline__ void conv_body(int cblk, const unsigned short* __restrict__ xT,
                                          const unsigned short* __restrict__ wT,
                                          const float* __restrict__ bb,
                                          const float* __restrict__ bng,
                                          const float* __restrict__ bnb,
                                          const float* __restrict__ bnm,
                                          const float* __restrict__ bnv,
                                          const unsigned short* __restrict__ zbuf,
                                          unsigned short* __restrict__ statb,
                                          float* __restrict__ out, char* smemc) {
  int nb = ((cblk & 7) << 8) | (cblk >> 3);  // XCD swizzle (2048 % 8 == 0)
  int ocb = nb & 1, y = (nb >> 1) & 127, b = nb >> 8;
  int lane = threadIdx.x & 63, wid = threadIdx.x >> 6;
  int m_l = lane & 15, kgrp = lane >> 4;

  unsigned short* xs = (unsigned short*)smemc;  // ring: 4 x 8320B row slots
  const char* zc = (const char*)zbuf;

  int g0 = wid * 130 + lane, g1 = g0 + 64, g2 = wid * 130 + 128 + lane;  // g2: lane<2
  int px0_ = g0 >> 2, k0_ = g0 & 3, s0_ = k0_ ^ ((px0_ >> 1) & 3), gx0 = px0_ - 1;
  int px1_ = g1 >> 2, k1_ = g1 & 3, s1_ = k1_ ^ ((px1_ >> 1) & 3), gx1 = px1_ - 1;
  int px2_ = g2 >> 2, k2_ = g2 & 3, s2_ = k2_ ^ ((px2_ >> 1) & 3), gx2 = px2_ - 1;
  bool ok0 = (unsigned)gx0 < 128u, ok1 = (unsigned)gx1 < 128u, ok2 = (unsigned)gx2 < 128u;
  int off0 = gx0 * 512 + s0_ * 16, off1 = gx1 * 512 + s1_ * 16, off2 = gx2 * 512 + s2_ * 16;
  int d0 = (wid * 130) * 16, d1 = d0 + 1024, d2 = d0 + 2048;

#define STAGE_ROW(slotB_, cbn_, khn_)                                                       \
  do {                                                                                      \
    int gy_ = y + (khn_)-1;                                                                 \
    bool gyok_ = ((unsigned)gy_ < 128u);                                                    \
    const char* rb_ =                                                                       \
        (const char*)xT + (((size_t)b << 14) + (size_t)(gy_ & 127) * 128) * 512 + (cbn_)*64;\
    gload16((gyok_ && ok0) ? rb_ + off0 : zc, smemc + (slotB_) + d0);                       \
    gload16((gyok_ && ok1) ? rb_ + off1 : zc, smemc + (slotB_) + d1);                       \
    if (lane < 2) gload16((gyok_ && ok2) ? rb_ + off2 : zc, smemc + (slotB_) + d2);         \
  } while (0)

  f32x4 acc[8][2];
#pragma unroll
  for (int mt = 0; mt < 8; ++mt)
#pragma unroll
    for (int nt = 0; nt < 2; ++nt) acc[mt][nt] = (f32x4)0.f;

  STAGE_ROW(0, 0, 0);
  STAGE_ROW(8320, 0, 1);
  STAGE_ROW(16640, 0, 2);
  STAGE_ROW(24960, 1, 0);

  int oc0 = ocb * 128 + wid * 32;
  const unsigned short* wTb = wT + ((size_t)(oc0 + m_l) * 32 + kgrp * 8);
  int khn = 1, cbn = 1;

#pragma unroll 1
  for (int P = 0; P < 12; ++P) {
    if (P < 11) {
      asm volatile("s_waitcnt vmcnt(6)" ::: "memory");
    } else {
      asm volatile("s_waitcnt vmcnt(0)" ::: "memory");
    }
    __builtin_amdgcn_s_barrier();
    asm volatile("" ::: "memory");
#pragma unroll
    for (int half = 0; half < 2; ++half) {
      int R = 2 * P + half;
      const unsigned short* xb = xs + (R & 3) * 4160;
#pragma unroll
      for (int kw = 0; kw < 3; ++kw) {
        bf16x8 bfrag[2];
        const unsigned short* wb = wTb + (size_t)(R * 3 + kw) * 8192;
#pragma unroll
        for (int nt = 0; nt < 2; ++nt) bfrag[nt] = *(const bf16x8*)(wb + nt * 512);
#pragma unroll
        for (int mt = 0; mt < 8; ++mt) {
          int apx = mt * 16 + m_l + kw;
          int kk = kgrp ^ ((apx >> 1) & 3);
          bf16x8 af =
              *(__attribute__((address_space(3))) bf16x8*)(&xb[apx * 32 + kk * 8]);
#pragma unroll
          for (int nt = 0; nt < 2; ++nt)
            acc[mt][nt] =
                __builtin_amdgcn_mfma_f32_16x16x32_bf16(af, bfrag[nt], acc[mt][nt], 0, 0, 0);
        }
      }
    }
    __builtin_amdgcn_s_barrier();
    asm volatile("" ::: "memory");
    if (P < 10) {
      STAGE_ROW((size_t)((2 * P + 4) & 3) * 8320, cbn, khn);
      ++khn;
      if (khn == 3) { khn = 0; ++cbn; }
      STAGE_ROW((size_t)((2 * P + 5) & 3) * 8320, cbn, khn);
      ++khn;
      if (khn == 3) { khn = 0; ++cbn; }
    }
  }
#undef STAGE_ROW

  float scale2[2], bias2[2];
#pragma unroll
  for (int nt = 0; nt < 2; ++nt) {
    int oc = oc0 + nt * 16 + m_l;
    float s = bng[oc] * rsqrtf(bnv[oc] + EPS_);
    scale2[nt] = s;
    bias2[nt] = bnb[oc] + (bb[oc] - bnm[oc]) * s;
  }
  if (statb) {
#pragma unroll
    for (int nt = 0; nt < 2; ++nt) {
      size_t obase = (((size_t)(b * 256 + oc0 + nt * 16 + m_l)) << 14) + y * 128 + kgrp * 4;
#pragma unroll
      for (int mt = 0; mt < 8; ++mt) {
        f32x4 v = acc[mt][nt];
        u16x4 o;
#pragma unroll
        for (int r = 0; r < 4; ++r) {
          float hv = v[r] * scale2[nt] + bias2[nt];
          o[r] = f2bf(hv * sigmoidf_(hv));
        }
        *(u16x4*)(statb + obase + mt * 16) = o;
      }
    }
  } else {
#pragma unroll
    for (int nt = 0; nt < 2; ++nt) {
      size_t obase = (((size_t)(b * 256 + oc0 + nt * 16 + m_l)) << 14) + y * 128 + kgrp * 4;
#pragma unroll
      for (int mt = 0; mt < 8; ++mt) {
        f32x4 v = acc[mt][nt];
        float o4[4];
#pragma unroll
        for (int r = 0; r < 4; ++r) {
          float hv = v[r] * scale2[nt] + bias2[nt];
          o4[r] = hv * sigmoidf_(hv);
        }
        *(f32x4*)(out + obase + mt * 16) = (f32x4){o4[0], o4[1], o4[2], o4[3]};
      }
    }
  }
}

// gate body: one block per batch image (8 blocks at the tail of dispatch B)
__device__ __forceinline__ void gate_body(int b, const float* __restrict__ partial,
                                          const float* __restrict__ gw,
                                          const float* __restrict__ gb,
                                          float* __restrict__ gout, char* smemc) {
  float* red = (float*)smemc;
  int t = threadIdx.x;
  float s = partial[b * 256 + t] * gw[t];
#pragma unroll
  for (int off = 32; off; off >>= 1) s += __shfl_down(s, off, 64);
  if ((t & 63) == 0) red[t >> 6] = s;
  __syncthreads();
  if (t == 0) {
    float tot = (red[0] + red[1]) + (red[2] + red[3]);
    gout[b] = sigmoidf_(tot * (1.f / 16384.f) + gb[0]);
  }
}

// ---------------------------------------------------------------- dispatch B
// [0,kgN): MFMA kernelgen; [kgN,kgN+2048): conv; tail 8 blocks: gate.
__global__ __launch_bounds__(256, 4) void fused_kernel(
    int kgN, const unsigned short* __restrict__ xT, const unsigned short* __restrict__ wT,
    const unsigned short* __restrict__ w1b, const unsigned short* __restrict__ w2b,
    const float* __restrict__ b1f, const float* __restrict__ b2p, float* __restrict__ kern,
    const float* __restrict__ bb, const float* __restrict__ bng, const float* __restrict__ bnb,
    const float* __restrict__ bnm, const float* __restrict__ bnv,
    const unsigned short* __restrict__ zbuf, unsigned short* __restrict__ statb,
    float* __restrict__ out, const float* __restrict__ partial, const float* __restrict__ gw,
    const float* __restrict__ gb, float* __restrict__ gout) {
  __shared__ char smem[33280];  // conv ring 33,280B; kg uses 30,848B
  int blk = (int)blockIdx.x;
  if (blk < kgN) {
    kernelgen_body(blk, xT, w1b, w2b, b1f, b2p, zbuf, kern, smem);
  } else if (blk < kgN + 2048) {
    conv_body(blk - kgN, xT, wT, bb, bng, bnb, bnm, bnv, zbuf, statb, out, smem);
  } else {
    gate_body(blk - kgN - 2048, partial, gw, gb, gout, smem);
  }
}

// ---------------------------------------------------------------- CARAFE + blend (dispatch C)
// 32-WIDE TILES: tile 16ch x 16y x 32x; patch [20 rows][36 px][16 ch] = 23,040B (same
// LDS/occupancy as before) but out/statb accesses are 128B per instruction (lanes 0-31
// cover 32 consecutive px). XCD-tile clustering; halo via global_load_lds; kern
// prefetch; statb write-only-out path with fp32-RMW fallback.
__global__ __launch_bounds__(256) void carafe_blend_kernel(
    const unsigned short* __restrict__ xT, const float* __restrict__ kern,
    const float* __restrict__ gq, const unsigned short* __restrict__ statb,
    float* __restrict__ out) {
  int blk = blockIdx.x;  // 4096
  int xcd = blk & 7, r = blk >> 3;
  int ocg = r & 15;
  int tile = (r >> 4) * 8 + xcd;  // 0..255
  int b = tile >> 5, rem = tile & 31;
  int by = rem >> 2, bx = rem & 3;  // by 0..7 (16 rows), bx 0..3 (32 px)
  __shared__ unsigned short xc[720 * 16];  // [20 rows x 36 px][16 ch]
  int lane = threadIdx.x & 63, wid = threadIdx.x >> 6;
  int lx = threadIdx.x & 31, ty = threadIdx.x >> 5;  // ty 0..7
  float gv = gq[b];
  int y0 = ty * 2;
  int gy0 = by * 16 + y0, gx = bx * 32 + lx;

  // kern prefetch (issued before staging DMA)
  float kv0[25], kv1[25];
  size_t kb = (((size_t)b * 25) << 14) + (size_t)gy0 * 128 + gx;
#pragma unroll
  for (int n = 0; n < 25; ++n) {
    kv0[n] = kern[kb + ((size_t)n << 14)];
    kv1[n] = kern[kb + ((size_t)n << 14) + 128];
  }

  // halo staging: 1440 granules of 16B; wave w covers [w*360, +360)
  int dstb = wid * 5760;
#pragma unroll
  for (int i = 0; i < 6; ++i) {
    int g = wid * 360 + i * 64 + lane;
    if (i < 5 || lane < 40) {
      int p = g >> 1, half = g & 1;
      int py = p / 36, pxx = p - py * 36;
      int yy = by * 16 + py - 2, xx = bx * 32 + pxx - 2;
      yy = yy < 0 ? -yy : (yy > 127 ? 254 - yy : yy);
      xx = xx < 0 ? -xx : (xx > 127 ? 254 - xx : xx);
      gload16((const char*)xT + ((size_t)((b << 14) + yy * 128 + xx) * 512) + ocg * 32 +
                  half * 16,
              (char*)xc + dstb + i * 1024);
    }
  }
  asm volatile("s_waitcnt vmcnt(0)" ::: "memory");
  __syncthreads();

  f32x2 car0[8], car1[8];
#pragma unroll
  for (int c = 0; c < 8; ++c) { car0[c] = (f32x2)0.f; car1[c] = (f32x2)0.f; }
#pragma unroll
  for (int n = 0; n < 25; ++n) {
    int ki = n / 5, kj = n - ki * 5;
    int p0 = (y0 + ki) * 36 + lx + kj;
    f32x2 kvv0 = (f32x2){kv0[n], kv0[n]}, kvv1 = (f32x2){kv1[n], kv1[n]};
    union { u16x8 s8; unsigned int u[4]; } a0, a1, b0, b1;
    a0.s8 = *(lds_u16x8*)(&xc[p0 * 16]);
    a1.s8 = *(lds_u16x8*)(&xc[p0 * 16 + 8]);
    b0.s8 = *(lds_u16x8*)(&xc[(p0 + 36) * 16]);
    b1.s8 = *(lds_u16x8*)(&xc[(p0 + 36) * 16 + 8]);
#pragma unroll
    for (int j = 0; j < 4; ++j) {
      f32x2 f0 = (f32x2){__uint_as_float(a0.u[j] << 16), __uint_as_float(a0.u[j] & 0xffff0000u)};
      f32x2 f1 = (f32x2){__uint_as_float(a1.u[j] << 16), __uint_as_float(a1.u[j] & 0xffff0000u)};
      f32x2 g0 = (f32x2){__uint_as_float(b0.u[j] << 16), __uint_as_float(b0.u[j] & 0xffff0000u)};
      f32x2 g1 = (f32x2){__uint_as_float(b1.u[j] << 16), __uint_as_float(b1.u[j] & 0xffff0000u)};
      car0[j] = pkfma_(f0, kvv0, car0[j]);
      car0[4 + j] = pkfma_(f1, kvv0, car0[4 + j]);
      car1[j] = pkfma_(g0, kvv1, car1[j]);
      car1[4 + j] = pkfma_(g1, kvv1, car1[4 + j]);
    }
  }
  if (statb) {
#pragma unroll
    for (int j = 0; j < 8; ++j) {
      size_t ob0 = (((size_t)(b * 256 + ocg * 16 + 2 * j)) << 14) + (size_t)gy0 * 128 + gx;
      size_t ob1 = ob0 + 16384;
      float s00 = bf2f(statb[ob0]), s01 = bf2f(statb[ob0 + 128]);
      float s10 = bf2f(statb[ob1]), s11 = bf2f(statb[ob1 + 128]);
      out[ob0] = fmaf(gv, car0[j].x - s00, s00);
      out[ob0 + 128] = fmaf(gv, car1[j].x - s01, s01);
      out[ob1] = fmaf(gv, car0[j].y - s10, s10);
      out[ob1 + 128] = fmaf(gv, car1[j].y - s11, s11);
    }
  } else {
#pragma unroll
    for (int j = 0; j < 8; ++j) {
      size_t ob0 = (((size_t)(b * 256 + ocg * 16 + 2 * j)) << 14) + (size_t)gy0 * 128 + gx;
      size_t ob1 = ob0 + 16384;
      float s00 = out[ob0], s01 = out[ob0 + 128];
      float s10 = out[ob1], s11 = out[ob1 + 128];
      out[ob0] = fmaf(gv, car0[j].x - s00, s00);
      out[ob0 + 128] = fmaf(gv, car1[j].x - s01, s01);
      out[ob1] = fmaf(gv, car0[j].y - s10, s10);
      out[ob1 + 128] = fmaf(gv, car1[j].y - s11, s11);
    }
  }
}

// ---------------------------------------------------------------- launcher
extern "C" void kernel_launch(void* const* d_in, const int* in_sizes, int n_in,
                              void* d_out, int out_size, void* d_ws, size_t ws_size,
                              hipStream_t stream) {
  const float* x      = (const float*)d_in[0];
  const float* ke_w1  = (const float*)d_in[1];
  const float* ke_b1  = (const float*)d_in[2];
  const float* ke_bng = (const float*)d_in[3];
  const float* ke_bnb = (const float*)d_in[4];
  const float* ke_bnm = (const float*)d_in[5];
  const float* ke_bnv = (const float*)d_in[6];
  const float* ke_w2  = (const float*)d_in[7];
  const float* ke_b2  = (const float*)d_in[8];
  const float* bs_w   = (const float*)d_in[9];
  const float* bs_b   = (const float*)d_in[10];
  const float* bs_bng = (const float*)d_in[11];
  const float* bs_bnb = (const float*)d_in[12];
  const float* bs_bnm = (const float*)d_in[13];
  const float* bs_bnv = (const float*)d_in[14];
  const float* g_w    = (const float*)d_in[15];
  const float* g_b    = (const float*)d_in[16];
  float* outp = (float*)d_out;

  char* ws = (char*)d_ws;
  float* kern        = (float*)(ws);                      // 13,107,200 B
  float* partial     = (float*)(ws + 13107200);           // 8,192 B
  float* gout        = (float*)(ws + 13115392);           // bytes 0-31 of 256B slot
  float* zbuff       = (float*)(ws + 13115392 + 128);     // 64B zero pad
  unsigned short* wT = (unsigned short*)(ws + 13115648);  // 1,179,648 B
  unsigned short* xT = (unsigned short*)(ws + 14295296);  // 67,108,864 B -> 81,404,160 total

  // kg MFMA tables (99,456 B in a 131,072 B slot) + optional bf16 static buffer
  // (67,108,864 B). statb enables write-only out in carafe (no RMW read).
  const size_t USED = 81404160;
  const size_t TBL = 131072;
  bool bigws = ws_size >= USED + TBL;
  bool bigws2 = ws_size >= USED + TBL + 67108864;
  unsigned short *w1b, *w2b;
  float *b1f, *b2p;
  if (bigws) {
    w1b = (unsigned short*)(ws + USED);
    w2b = (unsigned short*)(ws + USED + 81920);
    b1f = (float*)(ws + USED + 98304);
    b2p = (float*)(ws + USED + 99328);
  } else {
    w1b = (unsigned short*)((char*)d_out + 52428800);
    w2b = (unsigned short*)((char*)d_out + 52428800 + 81920);
    b1f = (float*)((char*)d_out + 52428800 + 98304);
    b2p = (float*)((char*)d_out + 52428800 + 99328);
  }
  unsigned short* statb = bigws2 ? (unsigned short*)(ws + USED + TBL) : nullptr;

  hipMemsetAsync(partial, 0, 2048 * sizeof(float), stream);  // GAP accumulators
  // dispatch A: transpose (2048) + prep (2497) overlapped
  prep_transpose_kernel<<<4545, 256, 0, stream>>>(x, xT, partial, bs_w, wT, ke_w1, ke_b1,
                                                  ke_bng, ke_bnb, ke_bnm, ke_bnv, ke_w2,
                                                  ke_b2, w1b, w2b, b1f, b2p, zbuff);
  if (bigws) {
    // dispatch B: kg 512 + conv 2048 + gate 8
    fused_kernel<<<2568, 256, 0, stream>>>(512, xT, wT, w1b, w2b, b1f, b2p, kern, bs_b,
                                           bs_bng, bs_bnb, bs_bnm, bs_bnv,
                                           (const unsigned short*)zbuff, statb, outp,
                                           partial, g_w, g_b, gout);
  } else {
    // serial fallback: tables live in d_out (dead until conv runs after kernelgen)
    fused_kernel<<<512, 256, 0, stream>>>(512, xT, wT, w1b, w2b, b1f, b2p, kern, bs_b,
                                          bs_bng, bs_bnb, bs_bnm, bs_bnv,
                                          (const unsigned short*)zbuff, statb, outp,
                                          partial, g_w, g_b, gout);
    fused_kernel<<<2056, 256, 0, stream>>>(0, xT, wT, w1b, w2b, b1f, b2p, kern, bs_b,
                                           bs_bng, bs_bnb, bs_bnm, bs_bnv,
                                           (const unsigned short*)zbuff, statb, outp,
                                           partial, g_w, g_b, gout);
  }
  carafe_blend_kernel<<<4096, 256, 0, stream>>>(xT, kern, gout, statb, outp);
}